// Round 6
// baseline (5433.023 us; speedup 1.0000x reference)
//
#include <hip/hip_runtime.h>
#include <hip/hip_bf16.h>

typedef unsigned short u16;
typedef unsigned char u8;
typedef unsigned int u32;
typedef __attribute__((ext_vector_type(8))) short bf16x8;
typedef __attribute__((ext_vector_type(4))) float f32x4;

__device__ __forceinline__ float us2f(u16 u){ return __uint_as_float(((unsigned)u)<<16); }
__device__ __forceinline__ u16 f2us(float f){
  __hip_bfloat16 h = __float2bfloat16(f);
  union { __hip_bfloat16 b; u16 s; } cv; cv.b = h; return cv.s;
}
__device__ __forceinline__ float gelu_f(float v){ return 0.5f*v*(1.f+erff(v*0.70710678118654752f)); }
__device__ __forceinline__ float sigm_f(float v){ return 1.f/(1.f+expf(-v)); }
// device-coherent (LLC point) dword ops: no cache-maintenance, per-access coherent
__device__ __forceinline__ u32 cld(const u32* p){
  return __hip_atomic_load(p, __ATOMIC_RELAXED, __HIP_MEMORY_SCOPE_AGENT);
}
__device__ __forceinline__ void cst(u32* p, u32 v){
  __hip_atomic_store(p, v, __ATOMIC_RELAXED, __HIP_MEMORY_SCOPE_AGENT);
}

#define BNSC 0.9999950000374997f  /* 1/sqrt(1+1e-5) */

__global__ void zero_kernel(unsigned* __restrict__ p, int n){
  int i = blockIdx.x*64 + threadIdx.x;
  if (i < n) p[i] = 0u;
}
// ---------------------------------------------------------------- converts
__global__ void f2b_kernel(const float* __restrict__ s, u16* __restrict__ d, int n){
  int i = blockIdx.x*256 + threadIdx.x;
  if (i < n) d[i] = f2us(s[i]);
}
// patch_fc_w (256,1152) k=c*9+pos  ->  k'=pos*128+c
__global__ void reorder_pf_kernel(const float* __restrict__ s, u16* __restrict__ d){
  int i = blockIdx.x*256 + threadIdx.x;
  if (i >= 256*1152) return;
  int o = i/1152, kp = i%1152, pos = kp>>7, c = kp&127;
  d[i] = f2us(s[o*1152 + c*9 + pos]);
}
// c2_w (128,64,3,3) -> [o][tap*64+ic]
__global__ void reorder_w2_kernel(const float* __restrict__ s, u16* __restrict__ d){
  int i = blockIdx.x*256 + threadIdx.x;
  if (i >= 128*576) return;
  int o = i/576, k = i%576, tap = k>>6, ic = k&63, ty = tap/3, tx = tap%3;
  d[i] = f2us(s[((o*64 + ic)*3 + ty)*3 + tx]);
}
// fc2_w (32,512) -> padded (64,512), bias padded to 64
__global__ void fc2pad_kernel(const float* __restrict__ w, const float* __restrict__ b,
                              u16* __restrict__ wd, float* __restrict__ bd){
  int i = blockIdx.x*256 + threadIdx.x;
  if (i < 64*512){ int o = i>>9, k = i&511; wd[i] = (o<32) ? f2us(w[o*512+k]) : (u16)0; }
  if (i < 64) bd[i] = (i<32) ? b[i] : 0.f;
}
// W1T[e][tap][o] = c1_w[o][e][tap]  (e<32)
__global__ void w1t_kernel(const float* __restrict__ c1w, float* __restrict__ d){
  int i = blockIdx.x*256 + threadIdx.x;
  if (i >= 32*9*64) return;
  int c = i/576, r = i%576, tap = r>>6, o = r&63;
  d[i] = c1w[(o*33 + c)*9 + tap];
}
// term2[p][op][o] = c1_b[o] + sum_taps mask(p,Y,X)*c1_w[o][32][tap]
__global__ void term2_kernel(const float* __restrict__ c1w, const float* __restrict__ c1b,
                             float* __restrict__ d){
  int blk = blockIdx.x, o = threadIdx.x;      // grid 169*25, block 64
  int p = blk/25, op = blk%25, oy = op/5, ox = op%5;
  int yp = p/13, xp = p%13;
  float acc = c1b[o];
  for (int dy=0; dy<3; dy++) for (int dx=0; dx<3; dx++){
    int Y = oy+dy-1, X = ox+dx-1;
    if (Y<0||Y>4||X<0||X>4) continue;
    int rr = yp + Y - 4, cc = xp + X - 2;
    bool m = (rr>=0) && (cc>=0) && (cc<13) && !(Y==4 && X>=2);
    if (m) acc += c1w[(o*33 + 32)*9 + dy*3 + dx];
  }
  d[((long)p*25 + op)*64 + o] = acc;
}
__global__ void s2_kernel(const float* __restrict__ g, float* __restrict__ s2){
  int i = threadIdx.x; if (i<128) s2[i] = g[i]*BNSC;
}
// mv = map_vec @ mv_w.T + mv_b : (128,256)
__global__ void mv_kernel(const float* __restrict__ mvec, const float* __restrict__ w,
                          const float* __restrict__ b, float* __restrict__ out){
  int bi = blockIdx.x, o = threadIdx.x;
  float acc = b[o];
  for (int k=0;k<32;k++) acc += mvec[bi*32+k]*w[o*32+k];
  out[bi*256+o] = acc;
}
// pos = [row_emb[y]|col_emb[x]] @ pos_w.T + pos_b : (169,256)
__global__ void pos_kernel(const float* __restrict__ re, const float* __restrict__ ce,
                           const float* __restrict__ w, const float* __restrict__ b,
                           float* __restrict__ out){
  int p = blockIdx.x, o = threadIdx.x;
  int y = p/13, x = p%13;
  const float* wr = w + o*512;
  float acc = b[o];
  for (int k=0;k<256;k++) acc += re[y*256+k]*wr[k];
  for (int k=0;k<256;k++) acc += ce[x*256+k]*wr[256+k];
  out[p*256+o] = acc;
}
// effective class grid per patch: ecls[n][Y*5+X]; where(mask,patch,0) -> masked = class 0
__global__ void ecls_kernel(const int* __restrict__ tm, u8* __restrict__ ec){
  int id = blockIdx.x*256 + threadIdx.x;
  if (id >= 21632*25) return;
  int n = id/25, q = id%25, Y = q/5, X = q%5;
  int b = n/169, p = n%169, yp = p/13, xp = p%13;
  int rr = yp + X - 4, cc = xp + Y - 2;          // class slot uses transposed mask (i=X,j=Y)
  int val = 0;
  if (rr>=0 && cc>=0 && cc<13 && !(X==4 && Y>=2)) val = tm[b*169 + rr*13 + cc];
  ec[id] = (u8)val;
}
// conv1 gather + BN + gelu -> c1out[local n][25][64] bf16; processes patches [nbase, nbase+10816)
__global__ __launch_bounds__(256) void conv1_kernel(
    const u8* __restrict__ ec, const float* __restrict__ w1t, const float* __restrict__ t2,
    const float* __restrict__ bn1g, const float* __restrict__ bn1b, u16* __restrict__ c1out,
    int nbase){
  __shared__ __align__(16) u16 w1s[32*9*64];
  __shared__ u8 ecs[32*25];
  const int tid = threadIdx.x, nl0 = blockIdx.x*32;
  for (int i=tid; i<32*9*64; i+=256) w1s[i] = f2us(w1t[i]);
  for (int i=tid; i<32*25;   i+=256) ecs[i] = ec[((long)nbase + nl0)*25 + i];
  __syncthreads();
  const int grp = tid>>6, o = tid&63;
  const float s1 = bn1g[o]*BNSC, t1 = bn1b[o];
  for (int it = grp; it < 800; it += 4){
    const int nl = it/25, op = it%25, oy = op/5, ox = op%5;
    const int n = nbase + nl0 + nl, p = n%169;
    float acc = t2[((long)p*25 + op)*64 + o];
    #pragma unroll
    for (int dy=0; dy<3; dy++)
      #pragma unroll
      for (int dx=0; dx<3; dx++){
        int Y = oy+dy-1, X = ox+dx-1;
        if (Y>=0 && Y<5 && X>=0 && X<5){
          int e = ecs[nl*25 + Y*5 + X];
          acc += us2f(w1s[(e*9 + dy*3+dx)*64 + o]);
        }
      }
    c1out[((long)(nl0+nl)*25 + op)*64 + o] = f2us(gelu_f(acc*s1 + t1));
  }
}

// ----------------------------------------------- generic bf16 GEMM C = A@W^T
// Block computes 64 rows x (64*NT) cols. A: rows at A+m*lda; W: NxK row-major.
// omode 0: outF/outB row-major with stride ldc (in-place safe when grid.x==1).
// omode 1: outB = giX layout [t][cblk][gate][b][16] with m=b*169+t, n=gate*512+cblk*16+jl.
template<int NT>
__global__ __launch_bounds__(256) void gemm_bt(
    const u16* A, long lda, const u16* __restrict__ W,
    const float* __restrict__ bias, const float* __restrict__ scale, const float* __restrict__ shift,
    float* outF, u16* outB, long ldc, int N, int K, int act, int omode){
  __shared__ __align__(16) u16 As[64][72];
  __shared__ __align__(16) u16 Ws[NT][64][72];
  const int tid = threadIdx.x, wv = tid>>6, lane = tid&63;
  const int quad = lane>>4, l16 = lane&15;
  const int bm = blockIdx.y, bn = blockIdx.x;
  f32x4 acc[NT*4];
  #pragma unroll
  for (int i=0;i<NT*4;i++) acc[i] = (f32x4){0.f,0.f,0.f,0.f};
  const int sm = tid>>2, sk = (tid&3)<<4;
  const long arow = (long)(bm*64 + sm)*lda;
  for (int kb = 0; kb < K; kb += 64){
    int4 a0 = *(const int4*)(A + arow + kb + sk);
    int4 a1 = *(const int4*)(A + arow + kb + sk + 8);
    *(int4*)&As[sm][sk]   = a0;  *(int4*)&As[sm][sk+8] = a1;
    #pragma unroll
    for (int wt=0; wt<NT; wt++){
      const long wrow = (long)(bn*(64*NT) + wt*64 + sm)*K;
      int4 w0 = *(const int4*)(W + wrow + kb + sk);
      int4 w1 = *(const int4*)(W + wrow + kb + sk + 8);
      *(int4*)&Ws[wt][sm][sk]   = w0;  *(int4*)&Ws[wt][sm][sk+8] = w1;
    }
    __syncthreads();
    #pragma unroll
    for (int ks = 0; ks < 64; ks += 32){
      bf16x8 af = *(const bf16x8*)(&As[wv*16 + l16][ks + quad*8]);
      #pragma unroll
      for (int wt=0; wt<NT; wt++)
        #pragma unroll
        for (int s=0; s<4; s++){
          bf16x8 bfv = *(const bf16x8*)(&Ws[wt][s*16 + l16][ks + quad*8]);
          acc[wt*4+s] = __builtin_amdgcn_mfma_f32_16x16x32_bf16(af, bfv, acc[wt*4+s], 0, 0, 0);
        }
    }
    __syncthreads();
  }
  const int mb = bm*64 + wv*16 + quad*4;
  #pragma unroll
  for (int wt=0; wt<NT; wt++)
    #pragma unroll
    for (int s=0; s<4; s++){
      const int n = bn*(64*NT) + wt*64 + s*16 + l16;
      const float bv = bias  ? bias[n]  : 0.f;
      const float sc = scale ? scale[n] : 1.f;
      const float sh = shift ? shift[n] : 0.f;
      #pragma unroll
      for (int r=0;r<4;r++){
        float v = acc[wt*4+s][r] + bv;
        v = v*sc + sh;
        if (act==1) v = fmaxf(v, 0.f);
        else if (act==2) v = gelu_f(v);
        if (omode == 1){
          const int m = mb + r, b = m/169, tt = m%169;
          const int gate = n>>9, cblk = (n>>4)&31, jl = n&15;
          outB[(((long)tt*32 + cblk)*3 + gate)*2048 + b*16 + jl] = f2us(v);
        } else {
          const long oo = (long)(mb + r)*ldc + n;
          if (outF) outF[oo] = v;
          if (outB) outB[oo] = f2us(v);
        }
      }
    }
}

// conv2 implicit-im2col GEMM: M rows (local n*9+py*3+px), K=576 (tap*64+ic), N=128
__global__ __launch_bounds__(256) void gemm_conv2(
    const u16* __restrict__ C1, const u16* __restrict__ W,
    const float* __restrict__ bias, const float* __restrict__ scale, const float* __restrict__ shift,
    u16* __restrict__ outB){
  __shared__ __align__(16) u16 As[64][72];
  __shared__ __align__(16) u16 Ws[64][72];
  const int tid = threadIdx.x, wv = tid>>6, lane = tid&63;
  const int quad = lane>>4, l16 = lane&15;
  const int bm = blockIdx.y, bn = blockIdx.x;
  f32x4 acc[4];
  #pragma unroll
  for (int i=0;i<4;i++) acc[i] = (f32x4){0.f,0.f,0.f,0.f};
  const int sm = tid>>2, sk = (tid&3)<<4;
  const int g = bm*64 + sm, n_ = g/9, pos = g%9, py = pos/3, px = pos%3;
  const long wrow = (long)(bn*64 + sm)*576;
  for (int tap = 0; tap < 9; tap++){
    const int kb = tap*64;
    const long aoff = ((long)n_*25 + (py + tap/3)*5 + (px + tap%3))*64 + sk;
    int4 a0 = *(const int4*)(C1 + aoff);
    int4 a1 = *(const int4*)(C1 + aoff + 8);
    int4 w0 = *(const int4*)(W + wrow + kb + sk);
    int4 w1 = *(const int4*)(W + wrow + kb + sk + 8);
    *(int4*)&As[sm][sk]   = a0;  *(int4*)&As[sm][sk+8] = a1;
    *(int4*)&Ws[sm][sk]   = w0;  *(int4*)&Ws[sm][sk+8] = w1;
    __syncthreads();
    #pragma unroll
    for (int ks = 0; ks < 64; ks += 32){
      bf16x8 af = *(const bf16x8*)(&As[wv*16 + l16][ks + quad*8]);
      #pragma unroll
      for (int nt=0; nt<4; nt++){
        bf16x8 bfv = *(const bf16x8*)(&Ws[nt*16 + l16][ks + quad*8]);
        acc[nt] = __builtin_amdgcn_mfma_f32_16x16x32_bf16(af, bfv, acc[nt], 0, 0, 0);
      }
    }
    __syncthreads();
  }
  const int mb = bm*64 + wv*16 + quad*4;
  #pragma unroll
  for (int nt=0; nt<4; nt++){
    const int n = bn*64 + nt*16 + l16;
    const float bv = bias[n], sc = scale[n], sh = shift[n];
    #pragma unroll
    for (int r=0;r<4;r++){
      float v = (acc[nt][r] + bv)*sc + sh;
      outB[(long)(mb + r)*128 + n] = f2us(gelu_f(v));
    }
  }
}

// tokens -> h bf16 [86528][256]; fills slots 0..2 (pf slot written by patch_fc gemm)
__global__ void token_kernel(const int* __restrict__ tm, const float* __restrict__ te,
                             const float* __restrict__ mv, const float* __restrict__ pos,
                             u16* __restrict__ hB){
  const int n = blockIdx.x, k = threadIdx.x;
  const int b = n/169, p = n%169;
  const int prev = (p==0) ? 31 : tm[b*169 + p - 1];
  const long r0 = (long)n*1024;
  hB[r0 + k]        = f2us(te[prev*256 + k]);
  hB[r0 + 256 + k]  = f2us(mv[b*256 + k]);
  hB[r0 + 512 + k]  = f2us(pos[p*256 + k]);
}

// attention: seq of 4 tokens, 2 heads x 128; one wave per (local) sequence
__global__ __launch_bounds__(256) void attn_kernel(const u16* __restrict__ qkv, u16* o){
  const int n = blockIdx.x*4 + (threadIdx.x>>6);
  const int lane = threadIdx.x & 63;
  float qv[4][2][2], kv[4][2][2], vv[4][2][2];
  #pragma unroll
  for (int tok=0; tok<4; tok++){
    const long rb = (long)(n*4+tok)*768;
    #pragma unroll
    for (int h=0; h<2; h++){
      unsigned u;
      u = *(const unsigned*)(qkv + rb +        h*128 + 2*lane); qv[tok][h][0]=us2f(u&0xffff); qv[tok][h][1]=us2f(u>>16);
      u = *(const unsigned*)(qkv + rb + 256 +  h*128 + 2*lane); kv[tok][h][0]=us2f(u&0xffff); kv[tok][h][1]=us2f(u>>16);
      u = *(const unsigned*)(qkv + rb + 512 +  h*128 + 2*lane); vv[tok][h][0]=us2f(u&0xffff); vv[tok][h][1]=us2f(u>>16);
    }
  }
  float sc[2][4][4];
  #pragma unroll
  for (int h=0; h<2; h++)
    #pragma unroll
    for (int qt=0; qt<4; qt++)
      #pragma unroll
      for (int kt=0; kt<4; kt++){
        float p_ = qv[qt][h][0]*kv[kt][h][0] + qv[qt][h][1]*kv[kt][h][1];
        for (int off=32; off; off>>=1) p_ += __shfl_xor(p_, off);
        sc[h][qt][kt] = p_ * 0.08838834764831845f;
      }
  #pragma unroll
  for (int h=0; h<2; h++)
    #pragma unroll
    for (int qt=0; qt<4; qt++){
      float m = fmaxf(fmaxf(sc[h][qt][0],sc[h][qt][1]),fmaxf(sc[h][qt][2],sc[h][qt][3]));
      float s = 0.f;
      #pragma unroll
      for (int kt=0; kt<4; kt++){ sc[h][qt][kt] = expf(sc[h][qt][kt]-m); s += sc[h][qt][kt]; }
      float inv = 1.f/s;
      #pragma unroll
      for (int kt=0; kt<4; kt++) sc[h][qt][kt] *= inv;
    }
  #pragma unroll
  for (int qt=0; qt<4; qt++)
    #pragma unroll
    for (int h=0; h<2; h++){
      float o0=0.f, o1=0.f;
      #pragma unroll
      for (int kt=0; kt<4; kt++){ o0 += sc[h][qt][kt]*vv[kt][h][0]; o1 += sc[h][qt][kt]*vv[kt][h][1]; }
      unsigned u = (unsigned)f2us(o0) | ((unsigned)f2us(o1)<<16);
      *(unsigned*)(o + (long)(n*4+qt)*256 + h*128 + 2*lane) = u;
    }
}

// LayerNorm (wave per row): out = [gelu](LN(delta [+ base]))  — delta bf16
template<int NPL>
__global__ __launch_bounds__(256) void ln_kernel(
    const u16* __restrict__ delta, const u16* __restrict__ base,
    const float* __restrict__ g, const float* __restrict__ b,
    u16* __restrict__ out, int do_gelu){
  const int D = NPL*64;
  const int row = blockIdx.x*4 + (threadIdx.x>>6);
  const int lane = threadIdx.x & 63;
  const long ro = (long)row*D;
  float x[NPL];
  float s = 0.f;
  #pragma unroll
  for (int i=0;i<NPL;i++){
    float v = us2f(delta[ro + i*64 + lane]);
    if (base) v += us2f(base[ro + i*64 + lane]);
    x[i] = v; s += v;
  }
  for (int off=32; off; off>>=1) s += __shfl_xor(s, off);
  const float mean = s / D;
  float var = 0.f;
  #pragma unroll
  for (int i=0;i<NPL;i++){ float dd = x[i]-mean; var += dd*dd; }
  for (int off=32; off; off>>=1) var += __shfl_xor(var, off);
  const float rs = rsqrtf(var/D + 1e-5f);
  #pragma unroll
  for (int i=0;i<NPL;i++){
    float y = (x[i]-mean)*rs*g[i*64+lane] + b[i*64+lane];
    if (do_gelu) y = gelu_f(y);
    out[ro + i*64 + lane] = f2us(y);
  }
}

// GRU v4: 32 persistent WGs, WG c owns hidden cols [16c,16c+16), weights in LDS.
// gi pre-swizzled giX[t][c][gate][128][16] (plain cached loads, stays in L2 now).
// Exchange hx[t][c][128][16] via per-access device-coherent dword ops (sc0 sc1 at LLC),
// RELAXED-only barrier: no L2 writeback / invalidate anywhere in the loop.
__global__ __launch_bounds__(256) void gru_kernel(
    const u16* __restrict__ gix, const float* __restrict__ whh,
    const float* __restrict__ bhh, u16* __restrict__ hx, unsigned* __restrict__ bar){
  __shared__ __align__(16) u16 Wl[48][520];
  __shared__ __align__(16) u16 hbuf[2048];
  const int c = blockIdx.x, tid = threadIdx.x;
  const int wv = tid>>6, lane = tid&63, quad = lane>>4, l16 = lane&15;
  for (int idx = tid; idx < 48*512; idx += 256){
    int g = idx >> 9, k = idx & 511;
    int gate = g >> 4, jl = g & 15;
    Wl[g][k] = f2us(whh[((gate<<9) + (c<<4) + jl)*512 + k]);
  }
  const int j = (c<<4) + l16;
  const float bh_r = bhh[j], bh_z = bhh[512+j], bh_n = bhh[1024+j];
  __syncthreads();
  float hold[2][4] = {{0.f,0.f,0.f,0.f},{0.f,0.f,0.f,0.f}};
  const int jlo = (quad&1)*8, jhiadd = quad>>1;
  for (int t=0; t<169; t++){
    // prefetch this step's gi (contiguous 12KB block; cached, independent of barrier)
    const u16* gbase = gix + ((long)t*32 + c)*3*2048;
    float gr_[2][4], gz_[2][4], gn_[2][4];
    #pragma unroll
    for (int mt=0; mt<2; mt++)
      #pragma unroll
      for (int r=0; r<4; r++){
        const int b = (2*wv+mt)*16 + quad*4 + r;
        gr_[mt][r] = us2f(gbase[       b*16 + l16]);
        gz_[mt][r] = us2f(gbase[2048 + b*16 + l16]);
        gn_[mt][r] = us2f(gbase[4096 + b*16 + l16]);
      }
    if (t>0){
      if (tid==0){
        while (__hip_atomic_load(bar, __ATOMIC_RELAXED, __HIP_MEMORY_SCOPE_AGENT) < (unsigned)(32*t))
          __builtin_amdgcn_s_sleep(1);
      }
      __syncthreads();
    }
    f32x4 acc[2][3];
    #pragma unroll
    for (int mt=0; mt<2; mt++)
      #pragma unroll
      for (int g3=0; g3<3; g3++) acc[mt][g3] = (f32x4){0.f,0.f,0.f,0.f};
    if (t>0){
      const long tb = (long)(t-1)*65536;
      const int b0 = (2*wv+0)*16 + l16, b1 = (2*wv+1)*16 + l16;
      #pragma unroll
      for (int ks=0; ks<512; ks+=32){
        const long off = tb + ((ks>>4) + jhiadd)*2048 + jlo;
        union { u32 d[4]; bf16x8 v; } ua0, ua1;
        const u32* p0 = (const u32*)(hx + off + b0*16);
        const u32* p1 = (const u32*)(hx + off + b1*16);
        #pragma unroll
        for (int i=0;i<4;i++){ ua0.d[i] = cld(p0+i); ua1.d[i] = cld(p1+i); }
        #pragma unroll
        for (int g3=0; g3<3; g3++){
          bf16x8 bfv = *(const bf16x8*)(&Wl[g3*16 + l16][ks + quad*8]);
          acc[0][g3] = __builtin_amdgcn_mfma_f32_16x16x32_bf16(ua0.v, bfv, acc[0][g3], 0,0,0);
          acc[1][g3] = __builtin_amdgcn_mfma_f32_16x16x32_bf16(ua1.v, bfv, acc[1][g3], 0,0,0);
        }
      }
    }
    #pragma unroll
    for (int mt=0; mt<2; mt++)
      #pragma unroll
      for (int r=0; r<4; r++){
        const int b = (2*wv+mt)*16 + quad*4 + r;
        float rr = sigm_f(gr_[mt][r] + acc[mt][0][r] + bh_r);
        float zz = sigm_f(gz_[mt][r] + acc[mt][1][r] + bh_z);
        float nn = tanhf (gn_[mt][r] + rr*(acc[mt][2][r] + bh_n));
        float h = (1.f-zz)*nn + zz*hold[mt][r];
        hold[mt][r] = h;
        hbuf[b*16 + l16] = f2us(h);
      }
    __syncthreads();
    {
      // 1024 dwords, device-coherent write-through (4KB slab, line-disjoint per WG)
      u32* dst = (u32*)(hx + (long)t*65536 + c*2048) + tid*4;
      const u32* src = (const u32*)hbuf + tid*4;
      #pragma unroll
      for (int i=0;i<4;i++) cst(dst+i, src[i]);
    }
    asm volatile("s_waitcnt vmcnt(0)" ::: "memory");   // stores at LLC before release
    __syncthreads();
    if (tid==0) __hip_atomic_fetch_add(bar, 1u, __ATOMIC_RELAXED, __HIP_MEMORY_SCOPE_AGENT);
  }
}

// hx[t][c][128][16] -> hs[(t*128+b)*512 + j]
__global__ void unswz_kernel(const u16* __restrict__ hx, u16* __restrict__ hs){
  int i = blockIdx.x*256 + threadIdx.x;
  if (i >= 169*128*512) return;
  int t = i >> 16, rem = i & 65535;
  int b = rem >> 9, jj = rem & 511;
  hs[i] = hx[((long)t<<16) + ((jj>>4)<<11) + (b<<4) + (jj&15)];
}

// final transpose: out[b][o][t] = fcout[(t*128+b)*64 + o]
__global__ void outtr_kernel(const float* __restrict__ fc, float* __restrict__ out){
  int i = blockIdx.x*256 + threadIdx.x;
  if (i >= 128*32*169) return;
  int t = i % 169, rest = i/169, o = rest % 32, b = rest/32;
  out[i] = fc[((long)(t*128 + b))*64 + o];
}

// ---------------------------------------------------------------- host
extern "C" void kernel_launch(void* const* d_in, const int* in_sizes, int n_in,
                              void* d_out, int out_size, void* d_ws, size_t ws_size,
                              hipStream_t stream){
  (void)in_sizes; (void)n_in; (void)out_size;
  const float* map_vec = (const float*)d_in[0];
  const int*   tm      = (const int*)  d_in[1];
  const float* mv_w  = (const float*)d_in[2];
  const float* mv_b  = (const float*)d_in[3];
  const float* te    = (const float*)d_in[4];
  const float* row_e = (const float*)d_in[5];
  const float* col_e = (const float*)d_in[6];
  const float* pos_w = (const float*)d_in[7];
  const float* pos_b = (const float*)d_in[8];
  const float* c1_w  = (const float*)d_in[9];
  const float* c1_b  = (const float*)d_in[10];
  const float* bn1_g = (const float*)d_in[11];
  const float* bn1_b = (const float*)d_in[12];
  const float* c2_w  = (const float*)d_in[13];
  const float* c2_b  = (const float*)d_in[14];
  const float* bn2_g = (const float*)d_in[15];
  const float* bn2_b = (const float*)d_in[16];
  const float* pf_w  = (const float*)d_in[17];
  const float* pf_b  = (const float*)d_in[18];
  const float* qkv_w = (const float*)d_in[19];
  const float* qkv_b = (const float*)d_in[20];
  const float* out_w = (const float*)d_in[21];
  const float* out_b = (const float*)d_in[22];
  const float* ln1_g = (const float*)d_in[23];
  const float* ln1_b = (const float*)d_in[24];
  const float* ff1_w = (const float*)d_in[25];
  const float* ff1_b = (const float*)d_in[26];
  const float* ff2_w = (const float*)d_in[27];
  const float* ff2_b = (const float*)d_in[28];
  const float* ln2_g = (const float*)d_in[29];
  const float* ln2_b = (const float*)d_in[30];
  const float* g_wih = (const float*)d_in[31];
  const float* g_whh = (const float*)d_in[32];
  const float* g_bih = (const float*)d_in[33];
  const float* g_bhh = (const float*)d_in[34];
  const float* fc1_w = (const float*)d_in[35];
  const float* fc1_b = (const float*)d_in[36];
  const float* fln_g = (const float*)d_in[37];
  const float* fln_b = (const float*)d_in[38];
  const float* fc2_w = (const float*)d_in[39];
  const float* fc2_b = (const float*)d_in[40];

  char* ws = (char*)d_ws;
  // -------- static arena layout (bytes) --------
  constexpr size_t O_BAR  = 0;
  constexpr size_t O_QKVW = 256;
  constexpr size_t O_OUTW = O_QKVW + 1179648;
  constexpr size_t O_FF1W = O_OUTW + 393216;
  constexpr size_t O_FF2W = O_FF1W + 393216;
  constexpr size_t O_WIHW = O_FF2W + 393216;
  constexpr size_t O_FC1W = O_WIHW + 786432;
  constexpr size_t O_PFW  = O_FC1W + 524288;
  constexpr size_t O_W2K  = O_PFW  + 589824;
  constexpr size_t O_FC2W = O_W2K  + 147456;
  constexpr size_t O_FC2B = O_FC2W + 65536;
  constexpr size_t O_W1T  = O_FC2B + 256;
  constexpr size_t O_T2   = O_W1T  + 73728;
  constexpr size_t O_S2   = O_T2   + 1081600;
  constexpr size_t O_MV   = O_S2   + 512;
  constexpr size_t O_POS  = O_MV   + 131072;
  constexpr size_t O_ECLS = O_POS  + 173056;
  constexpr size_t O_R0   = ((O_ECLS + 540800 + 255)/256)*256;   // 6,474,240
  constexpr size_t R0_SZ  = 44302336;   // HB -> (HX | HS)
  constexpr size_t O_R1   = O_R0 + R0_SZ;   // C1OUTc -> OBUF -> GIX(spans R2) -> Y1,YB
  constexpr size_t R1_SZ  = 44302336;
  constexpr size_t O_R2   = O_R1 + R1_SZ;   // C2OUTc -> QKVC -> GIX tail -> FCOUT
  constexpr size_t R2_SZ  = 33226752;
  constexpr size_t ARENA_END = O_R2 + R2_SZ;   // 128,305,664 B (~122.4 MiB)
  if (ws_size < ARENA_END) return;   // diagnostic: clean absmax fail (1.46875) = ws too small
  const size_t O_HB    = O_R0;
  const size_t O_HX    = O_R0;                 // 22,151,168 exchange layout
  const size_t O_HS    = O_R0 + 22151168;      // 22,151,168 (t,b)-row-major
  const size_t O_C1OUT = O_R1;                 // 34.6 MB chunk
  const size_t O_OBUF  = O_R1;                 // 44.3 MB; in-place DELTA1; then F1/DELTA2
  const size_t O_GIX   = O_R1;                 // 66.45 MB bf16, spans R1+R2
  const size_t O_Y1    = O_R1;                 // 22.2 MB bf16 (GIX dead post-GRU)
  const size_t O_YB    = O_R1 + 22151168;
  const size_t O_C2OUT = O_R2;                 // 24.9 MB chunk
  const size_t O_QKVC  = O_R2;                 // 33.2 MB chunk
  const size_t O_FCOUT = O_R2;                 // 5.5 MB f32 (after GIX dead)

  zero_kernel<<<1, 64, 0, stream>>>((unsigned*)(ws + O_BAR), 64);

  // weight conversion / reorder
  f2b_kernel<<<(3*768*256)/256, 256, 0, stream>>>(qkv_w, (u16*)(ws+O_QKVW), 3*768*256);
  f2b_kernel<<<(3*256*256)/256, 256, 0, stream>>>(out_w, (u16*)(ws+O_OUTW), 3*256*256);
  f2b_kernel<<<(3*256*256)/256, 256, 0, stream>>>(ff1_w, (u16*)(ws+O_FF1W), 3*256*256);
  f2b_kernel<<<(3*256*256)/256, 256, 0, stream>>>(ff2_w, (u16*)(ws+O_FF2W), 3*256*256);
  f2b_kernel<<<(1536*256)/256, 256, 0, stream>>>(g_wih, (u16*)(ws+O_WIHW), 1536*256);
  f2b_kernel<<<(512*512)/256, 256, 0, stream>>>(fc1_w, (u16*)(ws+O_FC1W), 512*512);
  reorder_pf_kernel<<<(256*1152)/256, 256, 0, stream>>>(pf_w, (u16*)(ws+O_PFW));
  reorder_w2_kernel<<<(128*576)/256, 256, 0, stream>>>(c2_w, (u16*)(ws+O_W2K));
  fc2pad_kernel<<<(64*512)/256, 256, 0, stream>>>(fc2_w, fc2_b, (u16*)(ws+O_FC2W), (float*)(ws+O_FC2B));
  w1t_kernel<<<(32*9*64)/256, 256, 0, stream>>>(c1_w, (float*)(ws+O_W1T));
  term2_kernel<<<169*25, 64, 0, stream>>>(c1_w, c1_b, (float*)(ws+O_T2));
  s2_kernel<<<1, 128, 0, stream>>>(bn2_g, (float*)(ws+O_S2));

  // token pieces
  mv_kernel<<<128, 256, 0, stream>>>(map_vec, mv_w, mv_b, (float*)(ws+O_MV));
  pos_kernel<<<169, 256, 0, stream>>>(row_e, col_e, pos_w, pos_b, (float*)(ws+O_POS));
  ecls_kernel<<<(21632*25+255)/256, 256, 0, stream>>>(tm, (u8*)(ws+O_ECLS));
  token_kernel<<<21632, 256, 0, stream>>>(tm, te, (const float*)(ws+O_MV), (const float*)(ws+O_POS),
      (u16*)(ws+O_HB));

  // conv pipeline, 2 chunks of 64 batches (10816 patches each)
  for (int cc = 0; cc < 2; cc++){
    const int nbase = cc*10816;
    conv1_kernel<<<338, 256, 0, stream>>>((const u8*)(ws+O_ECLS), (const float*)(ws+O_W1T),
        (const float*)(ws+O_T2), bn1_g, bn1_b, (u16*)(ws+O_C1OUT), nbase);
    gemm_conv2<<<dim3(2,1521), 256, 0, stream>>>((const u16*)(ws+O_C1OUT), (const u16*)(ws+O_W2K),
        c2_b, (const float*)(ws+O_S2), bn2_b, (u16*)(ws+O_C2OUT));
    gemm_bt<4><<<dim3(1,169), 256, 0, stream>>>((const u16*)(ws+O_C2OUT), 1152, (const u16*)(ws+O_PFW),
        pf_b, nullptr, nullptr, nullptr, (u16*)(ws+O_HB) + (size_t)nbase*1024 + 768, 1024, 256, 1152, 0, 0);
  }

  // transformer layers
  for (int l=0; l<3; l++){
    for (int cc = 0; cc < 4; cc++){          // 21632 token-rows (5408 seqs) per chunk
      gemm_bt<4><<<dim3(3,338), 256, 0, stream>>>((const u16*)(ws+O_HB) + (size_t)cc*21632*256, 256,
          (const u16*)(ws+O_QKVW) + (size_t)l*768*256, qkv_b + l*768, nullptr, nullptr,
          nullptr, (u16*)(ws+O_QKVC), 768, 768, 256, 0, 0);
      attn_kernel<<<1352, 256, 0, stream>>>((const u16*)(ws+O_QKVC),
          (u16*)(ws+O_OBUF) + (size_t)cc*5408*4*256);
    }
    gemm_bt<4><<<dim3(1,1352), 256, 0, stream>>>((const u16*)(ws+O_OBUF), 256,
        (const u16*)(ws+O_OUTW) + (size_t)l*256*256, out_b + l*256, nullptr, nullptr,
        nullptr, (u16*)(ws+O_OBUF), 256, 256, 256, 0, 0);      // in-place -> DELTA1
    ln_kernel<4><<<21632, 256, 0, stream>>>((const u16*)(ws+O_OBUF), (const u16*)(ws+O_HB),
        ln1_g + l*256, ln1_b + l*256, (u16*)(ws+O_HB), 0);
    gemm_bt<4><<<dim3(1,1352), 256, 0, stream>>>((const u16*)(ws+O_HB), 256,
        (const u16*)(ws+O_FF1W) + (size_t)l*256*256, ff1_b + l*256, nullptr, nullptr,
        nullptr, (u16*)(ws+O_OBUF), 256, 256, 256, 1, 0);      // F1
    gemm_bt<4><<<dim3(1,1352), 256, 0, stream>>>((const u16*)(ws+O_OBUF), 256,
        (const u16*)(ws+O_FF2W) + (size_t)l*256*256, ff2_b + l*256, nullptr, nullptr,
        nullptr, (u16*)(ws+O_OBUF), 256, 256, 256, 0, 0);      // in-place -> DELTA2
    ln_kernel<4><<<21632, 256, 0, stream>>>((const u16*)(ws+O_OBUF), (const u16*)(ws+O_HB),
        ln2_g + l*256, ln2_b + l*256, (u16*)(ws+O_HB), 0);
  }

  // GRU input projection -> swizzled giX[t][c][gate][b][16] (omode=1)
  gemm_bt<4><<<dim3(6,338), 256, 0, stream>>>((const u16*)(ws+O_HB), 1024, (const u16*)(ws+O_WIHW),
      g_bih, nullptr, nullptr, nullptr, (u16*)(ws+O_GIX), 1536, 1536, 256, 0, 1);
  gru_kernel<<<32, 256, 0, stream>>>((const u16*)(ws+O_GIX), g_whh, g_bhh,
      (u16*)(ws+O_HX), (unsigned*)(ws+O_BAR));
  unswz_kernel<<<(169*128*512)/256, 256, 0, stream>>>((const u16*)(ws+O_HX), (u16*)(ws+O_HS));

  // head (rows ordered m = t*128+b)
  gemm_bt<4><<<dim3(2,338), 256, 0, stream>>>((const u16*)(ws+O_HS), 512, (const u16*)(ws+O_FC1W),
      fc1_b, nullptr, nullptr, nullptr, (u16*)(ws+O_Y1), 512, 512, 512, 0, 0);
  ln_kernel<8><<<5408, 256, 0, stream>>>((const u16*)(ws+O_Y1), nullptr, fln_g, fln_b,
      (u16*)(ws+O_YB), 1);
  gemm_bt<1><<<dim3(1,338), 256, 0, stream>>>((const u16*)(ws+O_YB), 512, (const u16*)(ws+O_FC2W),
      (const float*)(ws+O_FC2B), nullptr, nullptr, (float*)(ws+O_FCOUT), nullptr, 64, 64, 512, 0, 0);
  outtr_kernel<<<(128*32*169+255)/256, 256, 0, stream>>>((const float*)(ws+O_FCOUT), (float*)d_out);
}

// Round 8
// 3396.795 us; speedup vs baseline: 1.5995x; 1.5995x over previous
//
#include <hip/hip_runtime.h>
#include <hip/hip_bf16.h>

typedef unsigned short u16;
typedef unsigned char u8;
typedef unsigned int u32;
typedef __attribute__((ext_vector_type(8))) short bf16x8;
typedef __attribute__((ext_vector_type(4))) float f32x4;
typedef __attribute__((ext_vector_type(4))) unsigned int u32x4;

__device__ __forceinline__ float us2f(u16 u){ return __uint_as_float(((unsigned)u)<<16); }
__device__ __forceinline__ u16 f2us(float f){
  __hip_bfloat16 h = __float2bfloat16(f);
  union { __hip_bfloat16 b; u16 s; } cv; cv.b = h; return cv.s;
}
__device__ __forceinline__ float gelu_f(float v){ return 0.5f*v*(1.f+erff(v*0.70710678118654752f)); }
__device__ __forceinline__ float sigm_f(float v){ return 1.f/(1.f+expf(-v)); }

#define BNSC 0.9999950000374997f  /* 1/sqrt(1+1e-5) */

__global__ void zero_kernel(unsigned* __restrict__ p, int n){
  int i = blockIdx.x*64 + threadIdx.x;
  if (i < n) p[i] = 0u;
}
// ---------------------------------------------------------------- converts
__global__ void f2b_kernel(const float* __restrict__ s, u16* __restrict__ d, int n){
  int i = blockIdx.x*256 + threadIdx.x;
  if (i < n) d[i] = f2us(s[i]);
}
// patch_fc_w (256,1152) k=c*9+pos  ->  k'=pos*128+c
__global__ void reorder_pf_kernel(const float* __restrict__ s, u16* __restrict__ d){
  int i = blockIdx.x*256 + threadIdx.x;
  if (i >= 256*1152) return;
  int o = i/1152, kp = i%1152, pos = kp>>7, c = kp&127;
  d[i] = f2us(s[o*1152 + c*9 + pos]);
}
// c2_w (128,64,3,3) -> [o][tap*64+ic]
__global__ void reorder_w2_kernel(const float* __restrict__ s, u16* __restrict__ d){
  int i = blockIdx.x*256 + threadIdx.x;
  if (i >= 128*576) return;
  int o = i/576, k = i%576, tap = k>>6, ic = k&63, ty = tap/3, tx = tap%3;
  d[i] = f2us(s[((o*64 + ic)*3 + ty)*3 + tx]);
}
// fc2_w (32,512) -> padded (64,512), bias padded to 64
__global__ void fc2pad_kernel(const float* __restrict__ w, const float* __restrict__ b,
                              u16* __restrict__ wd, float* __restrict__ bd){
  int i = blockIdx.x*256 + threadIdx.x;
  if (i < 64*512){ int o = i>>9, k = i&511; wd[i] = (o<32) ? f2us(w[o*512+k]) : (u16)0; }
  if (i < 64) bd[i] = (i<32) ? b[i] : 0.f;
}
// W1T[e][tap][o] = c1_w[o][e][tap]  (e<32)
__global__ void w1t_kernel(const float* __restrict__ c1w, float* __restrict__ d){
  int i = blockIdx.x*256 + threadIdx.x;
  if (i >= 32*9*64) return;
  int c = i/576, r = i%576, tap = r>>6, o = r&63;
  d[i] = c1w[(o*33 + c)*9 + tap];
}
// term2[p][op][o] = c1_b[o] + sum_taps mask(p,Y,X)*c1_w[o][32][tap]
__global__ void term2_kernel(const float* __restrict__ c1w, const float* __restrict__ c1b,
                             float* __restrict__ d){
  int blk = blockIdx.x, o = threadIdx.x;      // grid 169*25, block 64
  int p = blk/25, op = blk%25, oy = op/5, ox = op%5;
  int yp = p/13, xp = p%13;
  float acc = c1b[o];
  for (int dy=0; dy<3; dy++) for (int dx=0; dx<3; dx++){
    int Y = oy+dy-1, X = ox+dx-1;
    if (Y<0||Y>4||X<0||X>4) continue;
    int rr = yp + Y - 4, cc = xp + X - 2;
    bool m = (rr>=0) && (cc>=0) && (cc<13) && !(Y==4 && X>=2);
    if (m) acc += c1w[(o*33 + 32)*9 + dy*3 + dx];
  }
  d[((long)p*25 + op)*64 + o] = acc;
}
__global__ void s2_kernel(const float* __restrict__ g, float* __restrict__ s2){
  int i = threadIdx.x; if (i<128) s2[i] = g[i]*BNSC;
}
// mv = map_vec @ mv_w.T + mv_b : (128,256)
__global__ void mv_kernel(const float* __restrict__ mvec, const float* __restrict__ w,
                          const float* __restrict__ b, float* __restrict__ out){
  int bi = blockIdx.x, o = threadIdx.x;
  float acc = b[o];
  for (int k=0;k<32;k++) acc += mvec[bi*32+k]*w[o*32+k];
  out[bi*256+o] = acc;
}
// pos = [row_emb[y]|col_emb[x]] @ pos_w.T + pos_b : (169,256)
__global__ void pos_kernel(const float* __restrict__ re, const float* __restrict__ ce,
                           const float* __restrict__ w, const float* __restrict__ b,
                           float* __restrict__ out){
  int p = blockIdx.x, o = threadIdx.x;
  int y = p/13, x = p%13;
  const float* wr = w + o*512;
  float acc = b[o];
  for (int k=0;k<256;k++) acc += re[y*256+k]*wr[k];
  for (int k=0;k<256;k++) acc += ce[x*256+k]*wr[256+k];
  out[p*256+o] = acc;
}
// effective class grid per patch: ecls[n][Y*5+X]; where(mask,patch,0) -> masked = class 0
__global__ void ecls_kernel(const int* __restrict__ tm, u8* __restrict__ ec){
  int id = blockIdx.x*256 + threadIdx.x;
  if (id >= 21632*25) return;
  int n = id/25, q = id%25, Y = q/5, X = q%5;
  int b = n/169, p = n%169, yp = p/13, xp = p%13;
  int rr = yp + X - 4, cc = xp + Y - 2;          // class slot uses transposed mask (i=X,j=Y)
  int val = 0;
  if (rr>=0 && cc>=0 && cc<13 && !(X==4 && Y>=2)) val = tm[b*169 + rr*13 + cc];
  ec[id] = (u8)val;
}
// conv1 gather + BN + gelu -> c1out[local n][25][64] bf16; processes patches [nbase, nbase+10816)
__global__ __launch_bounds__(256) void conv1_kernel(
    const u8* __restrict__ ec, const float* __restrict__ w1t, const float* __restrict__ t2,
    const float* __restrict__ bn1g, const float* __restrict__ bn1b, u16* __restrict__ c1out,
    int nbase){
  __shared__ __align__(16) u16 w1s[32*9*64];
  __shared__ u8 ecs[32*25];
  const int tid = threadIdx.x, nl0 = blockIdx.x*32;
  for (int i=tid; i<32*9*64; i+=256) w1s[i] = f2us(w1t[i]);
  for (int i=tid; i<32*25;   i+=256) ecs[i] = ec[((long)nbase + nl0)*25 + i];
  __syncthreads();
  const int grp = tid>>6, o = tid&63;
  const float s1 = bn1g[o]*BNSC, t1 = bn1b[o];
  for (int it = grp; it < 800; it += 4){
    const int nl = it/25, op = it%25, oy = op/5, ox = op%5;
    const int n = nbase + nl0 + nl, p = n%169;
    float acc = t2[((long)p*25 + op)*64 + o];
    #pragma unroll
    for (int dy=0; dy<3; dy++)
      #pragma unroll
      for (int dx=0; dx<3; dx++){
        int Y = oy+dy-1, X = ox+dx-1;
        if (Y>=0 && Y<5 && X>=0 && X<5){
          int e = ecs[nl*25 + Y*5 + X];
          acc += us2f(w1s[(e*9 + dy*3+dx)*64 + o]);
        }
      }
    c1out[((long)(nl0+nl)*25 + op)*64 + o] = f2us(gelu_f(acc*s1 + t1));
  }
}

// ----------------------------------------------- generic bf16 GEMM C = A@W^T
// Block computes 64 rows x (64*NT) cols. A: rows at A+m*lda; W: NxK row-major.
// omode 0: outF/outB row-major with stride ldc (in-place safe when grid.x==1).
// omode 1: outB = giX layout [t][cblk][gate][b][16] with m=b*169+t, n=gate*512+cblk*16+jl.
template<int NT>
__global__ __launch_bounds__(256) void gemm_bt(
    const u16* A, long lda, const u16* __restrict__ W,
    const float* __restrict__ bias, const float* __restrict__ scale, const float* __restrict__ shift,
    float* outF, u16* outB, long ldc, int N, int K, int act, int omode){
  __shared__ __align__(16) u16 As[64][72];
  __shared__ __align__(16) u16 Ws[NT][64][72];
  const int tid = threadIdx.x, wv = tid>>6, lane = tid&63;
  const int quad = lane>>4, l16 = lane&15;
  const int bm = blockIdx.y, bn = blockIdx.x;
  f32x4 acc[NT*4];
  #pragma unroll
  for (int i=0;i<NT*4;i++) acc[i] = (f32x4){0.f,0.f,0.f,0.f};
  const int sm = tid>>2, sk = (tid&3)<<4;
  const long arow = (long)(bm*64 + sm)*lda;
  for (int kb = 0; kb < K; kb += 64){
    int4 a0 = *(const int4*)(A + arow + kb + sk);
    int4 a1 = *(const int4*)(A + arow + kb + sk + 8);
    *(int4*)&As[sm][sk]   = a0;  *(int4*)&As[sm][sk+8] = a1;
    #pragma unroll
    for (int wt=0; wt<NT; wt++){
      const long wrow = (long)(bn*(64*NT) + wt*64 + sm)*K;
      int4 w0 = *(const int4*)(W + wrow + kb + sk);
      int4 w1 = *(const int4*)(W + wrow + kb + sk + 8);
      *(int4*)&Ws[wt][sm][sk]   = w0;  *(int4*)&Ws[wt][sm][sk+8] = w1;
    }
    __syncthreads();
    #pragma unroll
    for (int ks = 0; ks < 64; ks += 32){
      bf16x8 af = *(const bf16x8*)(&As[wv*16 + l16][ks + quad*8]);
      #pragma unroll
      for (int wt=0; wt<NT; wt++)
        #pragma unroll
        for (int s=0; s<4; s++){
          bf16x8 bfv = *(const bf16x8*)(&Ws[wt][s*16 + l16][ks + quad*8]);
          acc[wt*4+s] = __builtin_amdgcn_mfma_f32_16x16x32_bf16(af, bfv, acc[wt*4+s], 0, 0, 0);
        }
    }
    __syncthreads();
  }
  const int mb = bm*64 + wv*16 + quad*4;
  #pragma unroll
  for (int wt=0; wt<NT; wt++)
    #pragma unroll
    for (int s=0; s<4; s++){
      const int n = bn*(64*NT) + wt*64 + s*16 + l16;
      const float bv = bias  ? bias[n]  : 0.f;
      const float sc = scale ? scale[n] : 1.f;
      const float sh = shift ? shift[n] : 0.f;
      #pragma unroll
      for (int r=0;r<4;r++){
        float v = acc[wt*4+s][r] + bv;
        v = v*sc + sh;
        if (act==1) v = fmaxf(v, 0.f);
        else if (act==2) v = gelu_f(v);
        if (omode == 1){
          const int m = mb + r, b = m/169, tt = m%169;
          const int gate = n>>9, cblk = (n>>4)&31, jl = n&15;
          outB[(((long)tt*32 + cblk)*3 + gate)*2048 + b*16 + jl] = f2us(v);
        } else {
          const long oo = (long)(mb + r)*ldc + n;
          if (outF) outF[oo] = v;
          if (outB) outB[oo] = f2us(v);
        }
      }
    }
}

// conv2 implicit-im2col GEMM: M rows (local n*9+py*3+px), K=576 (tap*64+ic), N=128
__global__ __launch_bounds__(256) void gemm_conv2(
    const u16* __restrict__ C1, const u16* __restrict__ W,
    const float* __restrict__ bias, const float* __restrict__ scale, const float* __restrict__ shift,
    u16* __restrict__ outB){
  __shared__ __align__(16) u16 As[64][72];
  __shared__ __align__(16) u16 Ws[64][72];
  const int tid = threadIdx.x, wv = tid>>6, lane = tid&63;
  const int quad = lane>>4, l16 = lane&15;
  const int bm = blockIdx.y, bn = blockIdx.x;
  f32x4 acc[4];
  #pragma unroll
  for (int i=0;i<4;i++) acc[i] = (f32x4){0.f,0.f,0.f,0.f};
  const int sm = tid>>2, sk = (tid&3)<<4;
  const int g = bm*64 + sm, n_ = g/9, pos = g%9, py = pos/3, px = pos%3;
  const long wrow = (long)(bn*64 + sm)*576;
  for (int tap = 0; tap < 9; tap++){
    const int kb = tap*64;
    const long aoff = ((long)n_*25 + (py + tap/3)*5 + (px + tap%3))*64 + sk;
    int4 a0 = *(const int4*)(C1 + aoff);
    int4 a1 = *(const int4*)(C1 + aoff + 8);
    int4 w0 = *(const int4*)(W + wrow + kb + sk);
    int4 w1 = *(const int4*)(W + wrow + kb + sk + 8);
    *(int4*)&As[sm][sk]   = a0;  *(int4*)&As[sm][sk+8] = a1;
    *(int4*)&Ws[sm][sk]   = w0;  *(int4*)&Ws[sm][sk+8] = w1;
    __syncthreads();
    #pragma unroll
    for (int ks = 0; ks < 64; ks += 32){
      bf16x8 af = *(const bf16x8*)(&As[wv*16 + l16][ks + quad*8]);
      #pragma unroll
      for (int nt=0; nt<4; nt++){
        bf16x8 bfv = *(const bf16x8*)(&Ws[nt*16 + l16][ks + quad*8]);
        acc[nt] = __builtin_amdgcn_mfma_f32_16x16x32_bf16(af, bfv, acc[nt], 0, 0, 0);
      }
    }
    __syncthreads();
  }
  const int mb = bm*64 + wv*16 + quad*4;
  #pragma unroll
  for (int nt=0; nt<4; nt++){
    const int n = bn*64 + nt*16 + l16;
    const float bv = bias[n], sc = scale[n], sh = shift[n];
    #pragma unroll
    for (int r=0;r<4;r++){
      float v = (acc[nt][r] + bv)*sc + sh;
      outB[(long)(mb + r)*128 + n] = f2us(gelu_f(v));
    }
  }
}

// tokens -> h bf16 [86528][256]; fills slots 0..2 (pf slot written by patch_fc gemm)
__global__ void token_kernel(const int* __restrict__ tm, const float* __restrict__ te,
                             const float* __restrict__ mv, const float* __restrict__ pos,
                             u16* __restrict__ hB){
  const int n = blockIdx.x, k = threadIdx.x;
  const int b = n/169, p = n%169;
  const int prev = (p==0) ? 31 : tm[b*169 + p - 1];
  const long r0 = (long)n*1024;
  hB[r0 + k]        = f2us(te[prev*256 + k]);
  hB[r0 + 256 + k]  = f2us(mv[b*256 + k]);
  hB[r0 + 512 + k]  = f2us(pos[p*256 + k]);
}

// attention: seq of 4 tokens, 2 heads x 128; one wave per (local) sequence
__global__ __launch_bounds__(256) void attn_kernel(const u16* __restrict__ qkv, u16* o){
  const int n = blockIdx.x*4 + (threadIdx.x>>6);
  const int lane = threadIdx.x & 63;
  float qv[4][2][2], kv[4][2][2], vv[4][2][2];
  #pragma unroll
  for (int tok=0; tok<4; tok++){
    const long rb = (long)(n*4+tok)*768;
    #pragma unroll
    for (int h=0; h<2; h++){
      unsigned u;
      u = *(const unsigned*)(qkv + rb +        h*128 + 2*lane); qv[tok][h][0]=us2f(u&0xffff); qv[tok][h][1]=us2f(u>>16);
      u = *(const unsigned*)(qkv + rb + 256 +  h*128 + 2*lane); kv[tok][h][0]=us2f(u&0xffff); kv[tok][h][1]=us2f(u>>16);
      u = *(const unsigned*)(qkv + rb + 512 +  h*128 + 2*lane); vv[tok][h][0]=us2f(u&0xffff); vv[tok][h][1]=us2f(u>>16);
    }
  }
  float sc[2][4][4];
  #pragma unroll
  for (int h=0; h<2; h++)
    #pragma unroll
    for (int qt=0; qt<4; qt++)
      #pragma unroll
      for (int kt=0; kt<4; kt++){
        float p_ = qv[qt][h][0]*kv[kt][h][0] + qv[qt][h][1]*kv[kt][h][1];
        for (int off=32; off; off>>=1) p_ += __shfl_xor(p_, off);
        sc[h][qt][kt] = p_ * 0.08838834764831845f;
      }
  #pragma unroll
  for (int h=0; h<2; h++)
    #pragma unroll
    for (int qt=0; qt<4; qt++){
      float m = fmaxf(fmaxf(sc[h][qt][0],sc[h][qt][1]),fmaxf(sc[h][qt][2],sc[h][qt][3]));
      float s = 0.f;
      #pragma unroll
      for (int kt=0; kt<4; kt++){ sc[h][qt][kt] = expf(sc[h][qt][kt]-m); s += sc[h][qt][kt]; }
      float inv = 1.f/s;
      #pragma unroll
      for (int kt=0; kt<4; kt++) sc[h][qt][kt] *= inv;
    }
  #pragma unroll
  for (int qt=0; qt<4; qt++)
    #pragma unroll
    for (int h=0; h<2; h++){
      float o0=0.f, o1=0.f;
      #pragma unroll
      for (int kt=0; kt<4; kt++){ o0 += sc[h][qt][kt]*vv[kt][h][0]; o1 += sc[h][qt][kt]*vv[kt][h][1]; }
      unsigned u = (unsigned)f2us(o0) | ((unsigned)f2us(o1)<<16);
      *(unsigned*)(o + (long)(n*4+qt)*256 + h*128 + 2*lane) = u;
    }
}

// LayerNorm (wave per row): out = [gelu](LN(delta [+ base]))  — delta bf16
template<int NPL>
__global__ __launch_bounds__(256) void ln_kernel(
    const u16* __restrict__ delta, const u16* __restrict__ base,
    const float* __restrict__ g, const float* __restrict__ b,
    u16* __restrict__ out, int do_gelu){
  const int D = NPL*64;
  const int row = blockIdx.x*4 + (threadIdx.x>>6);
  const int lane = threadIdx.x & 63;
  const long ro = (long)row*D;
  float x[NPL];
  float s = 0.f;
  #pragma unroll
  for (int i=0;i<NPL;i++){
    float v = us2f(delta[ro + i*64 + lane]);
    if (base) v += us2f(base[ro + i*64 + lane]);
    x[i] = v; s += v;
  }
  for (int off=32; off; off>>=1) s += __shfl_xor(s, off);
  const float mean = s / D;
  float var = 0.f;
  #pragma unroll
  for (int i=0;i<NPL;i++){ float dd = x[i]-mean; var += dd*dd; }
  for (int off=32; off; off>>=1) var += __shfl_xor(var, off);
  const float rs = rsqrtf(var/D + 1e-5f);
  #pragma unroll
  for (int i=0;i<NPL;i++){
    float y = (x[i]-mean)*rs*g[i*64+lane] + b[i*64+lane];
    if (do_gelu) y = gelu_f(y);
    out[ro + i*64 + lane] = f2us(y);
  }
}

// GRU v5b: 32 persistent WGs, WG c owns hidden cols [16c,16c+16), weights in LDS.
// Maintenance-free coherence (validated R6); h reads/writes are WIDE inline-asm
// sc0 sc1 b128 ops, all 32 loads in flight before one vmcnt(0) drain.
__global__ __launch_bounds__(256) void gru_kernel(
    const u16* __restrict__ gix, const float* __restrict__ whh,
    const float* __restrict__ bhh, u16* __restrict__ hx, unsigned* __restrict__ bar){
  __shared__ __align__(16) u16 Wl[48][520];
  __shared__ __align__(16) u16 hbuf[2048];
  const int c = blockIdx.x, tid = threadIdx.x;
  const int wv = tid>>6, lane = tid&63, quad = lane>>4, l16 = lane&15;
  for (int idx = tid; idx < 48*512; idx += 256){
    int g = idx >> 9, k = idx & 511;
    int gate = g >> 4, jl = g & 15;
    Wl[g][k] = f2us(whh[((gate<<9) + (c<<4) + jl)*512 + k]);
  }
  const int j = (c<<4) + l16;
  const float bh_r = bhh[j], bh_z = bhh[512+j], bh_n = bhh[1024+j];
  __syncthreads();
  float hold[2][4] = {{0.f,0.f,0.f,0.f},{0.f,0.f,0.f,0.f}};
  const int jlo = (quad&1)*8, jhiadd = quad>>1;
  for (int t=0; t<169; t++){
    // prefetch this step's gi (contiguous 12KB block; cached; independent of barrier)
    const u16* gbase = gix + ((long)t*32 + c)*3*2048;
    float gr_[2][4], gz_[2][4], gn_[2][4];
    #pragma unroll
    for (int mt=0; mt<2; mt++)
      #pragma unroll
      for (int r=0; r<4; r++){
        const int b = (2*wv+mt)*16 + quad*4 + r;
        gr_[mt][r] = us2f(gbase[       b*16 + l16]);
        gz_[mt][r] = us2f(gbase[2048 + b*16 + l16]);
        gn_[mt][r] = us2f(gbase[4096 + b*16 + l16]);
      }
    if (t>0){
      if (tid==0){
        while (__hip_atomic_load(bar, __ATOMIC_RELAXED, __HIP_MEMORY_SCOPE_AGENT) < (unsigned)(32*t))
          __builtin_amdgcn_s_sleep(1);
      }
      __syncthreads();
    }
    f32x4 acc[2][3];
    #pragma unroll
    for (int mt=0; mt<2; mt++)
      #pragma unroll
      for (int g3=0; g3<3; g3++) acc[mt][g3] = (f32x4){0.f,0.f,0.f,0.f};
    if (t>0){
      const long tb = (long)(t-1)*65536;
      const int b0 = (2*wv+0)*16 + l16, b1 = (2*wv+1)*16 + l16;
      bf16x8 av0[16], av1[16];
      // issue all 32 coherent b128 loads (bypass stale L1/L2, read LLC), fully pipelined
      #pragma unroll
      for (int ii=0; ii<16; ii++){
        const long off = tb + (long)(ii*2 + jhiadd)*2048 + jlo;
        const u16* p0 = hx + off + b0*16;
        const u16* p1 = hx + off + b1*16;
        asm volatile("global_load_dwordx4 %0, %1, off sc0 sc1" : "=v"(av0[ii]) : "v"(p0));
        asm volatile("global_load_dwordx4 %0, %1, off sc0 sc1" : "=v"(av1[ii]) : "v"(p1));
      }
      asm volatile("s_waitcnt vmcnt(0)" ::: "memory");
      #pragma unroll
      for (int ii=0; ii<16; ii++){            // tie values past the waitcnt (zero-cost)
        asm volatile("" : "+v"(av0[ii]));
        asm volatile("" : "+v"(av1[ii]));
      }
      #pragma unroll
      for (int ii=0; ii<16; ii++){
        const int ks = ii*32;
        #pragma unroll
        for (int g3=0; g3<3; g3++){
          bf16x8 bfv = *(const bf16x8*)(&Wl[g3*16 + l16][ks + quad*8]);
          acc[0][g3] = __builtin_amdgcn_mfma_f32_16x16x32_bf16(av0[ii], bfv, acc[0][g3], 0,0,0);
          acc[1][g3] = __builtin_amdgcn_mfma_f32_16x16x32_bf16(av1[ii], bfv, acc[1][g3], 0,0,0);
        }
      }
    }
    #pragma unroll
    for (int mt=0; mt<2; mt++)
      #pragma unroll
      for (int r=0; r<4; r++){
        const int b = (2*wv+mt)*16 + quad*4 + r;
        float rr = sigm_f(gr_[mt][r] + acc[mt][0][r] + bh_r);
        float zz = sigm_f(gz_[mt][r] + acc[mt][1][r] + bh_z);
        float nn = tanhf (gn_[mt][r] + rr*(acc[mt][2][r] + bh_n));
        float h = (1.f-zz)*nn + zz*hold[mt][r];
        hold[mt][r] = h;
        hbuf[b*16 + l16] = f2us(h);
      }
    __syncthreads();
    {
      // wave writes 4KB contiguous: full 64B lines, coherent at LLC
      u16* dst = hx + (long)t*65536 + c*2048 + tid*8;
      u32x4 val = *(const u32x4*)((const u32*)hbuf + tid*4);
      asm volatile("global_store_dwordx4 %0, %1, off sc0 sc1" :: "v"(dst), "v"(val) : "memory");
    }
    asm volatile("s_waitcnt vmcnt(0)" ::: "memory");   // stores at LLC before release
    __syncthreads();
    if (tid==0) __hip_atomic_fetch_add(bar, 1u, __ATOMIC_RELAXED, __HIP_MEMORY_SCOPE_AGENT);
  }
}

// hx[t][c][128][16] -> hs[(t*128+b)*512 + j]
__global__ void unswz_kernel(const u16* __restrict__ hx, u16* __restrict__ hs){
  int i = blockIdx.x*256 + threadIdx.x;
  if (i >= 169*128*512) return;
  int t = i >> 16, rem = i & 65535;
  int b = rem >> 9, jj = rem & 511;
  hs[i] = hx[((long)t<<16) + ((jj>>4)<<11) + (b<<4) + (jj&15)];
}

// final transpose: out[b][o][t] = fcout[(t*128+b)*64 + o]
__global__ void outtr_kernel(const float* __restrict__ fc, float* __restrict__ out){
  int i = blockIdx.x*256 + threadIdx.x;
  if (i >= 128*32*169) return;
  int t = i % 169, rest = i/169, o = rest % 32, b = rest/32;
  out[i] = fc[((long)(t*128 + b))*64 + o];
}

// ---------------------------------------------------------------- host
extern "C" void kernel_launch(void* const* d_in, const int* in_sizes, int n_in,
                              void* d_out, int out_size, void* d_ws, size_t ws_size,
                              hipStream_t stream){
  (void)in_sizes; (void)n_in; (void)out_size;
  const float* map_vec = (const float*)d_in[0];
  const int*   tm      = (const int*)  d_in[1];
  const float* mv_w  = (const float*)d_in[2];
  const float* mv_b  = (const float*)d_in[3];
  const float* te    = (const float*)d_in[4];
  const float* row_e = (const float*)d_in[5];
  const float* col_e = (const float*)d_in[6];
  const float* pos_w = (const float*)d_in[7];
  const float* pos_b = (const float*)d_in[8];
  const float* c1_w  = (const float*)d_in[9];
  const float* c1_b  = (const float*)d_in[10];
  const float* bn1_g = (const float*)d_in[11];
  const float* bn1_b = (const float*)d_in[12];
  const float* c2_w  = (const float*)d_in[13];
  const float* c2_b  = (const float*)d_in[14];
  const float* bn2_g = (const float*)d_in[15];
  const float* bn2_b = (const float*)d_in[16];
  const float* pf_w  = (const float*)d_in[17];
  const float* pf_b  = (const float*)d_in[18];
  const float* qkv_w = (const float*)d_in[19];
  const float* qkv_b = (const float*)d_in[20];
  const float* out_w = (const float*)d_in[21];
  const float* out_b = (const float*)d_in[22];
  const float* ln1_g = (const float*)d_in[23];
  const float* ln1_b = (const float*)d_in[24];
  const float* ff1_w = (const float*)d_in[25];
  const float* ff1_b = (const float*)d_in[26];
  const float* ff2_w = (const float*)d_in[27];
  const float* ff2_b = (const float*)d_in[28];
  const float* ln2_g = (const float*)d_in[29];
  const float* ln2_b = (const float*)d_in[30];
  const float* g_wih = (const float*)d_in[31];
  const float* g_whh = (const float*)d_in[32];
  const float* g_bih = (const float*)d_in[33];
  const float* g_bhh = (const float*)d_in[34];
  const float* fc1_w = (const float*)d_in[35];
  const float* fc1_b = (const float*)d_in[36];
  const float* fln_g = (const float*)d_in[37];
  const float* fln_b = (const float*)d_in[38];
  const float* fc2_w = (const float*)d_in[39];
  const float* fc2_b = (const float*)d_in[40];

  char* ws = (char*)d_ws;
  // -------- static arena layout (bytes) --------
  constexpr size_t O_BAR  = 0;
  constexpr size_t O_QKVW = 256;
  constexpr size_t O_OUTW = O_QKVW + 1179648;
  constexpr size_t O_FF1W = O_OUTW + 393216;
  constexpr size_t O_FF2W = O_FF1W + 393216;
  constexpr size_t O_WIHW = O_FF2W + 393216;
  constexpr size_t O_FC1W = O_WIHW + 786432;
  constexpr size_t O_PFW  = O_FC1W + 524288;
  constexpr size_t O_W2K  = O_PFW  + 589824;
  constexpr size_t O_FC2W = O_W2K  + 147456;
  constexpr size_t O_FC2B = O_FC2W + 65536;
  constexpr size_t O_W1T  = O_FC2B + 256;
  constexpr size_t O_T2   = O_W1T  + 73728;
  constexpr size_t O_S2   = O_T2   + 1081600;
  constexpr size_t O_MV   = O_S2   + 512;
  constexpr size_t O_POS  = O_MV   + 131072;
  constexpr size_t O_ECLS = O_POS  + 173056;
  constexpr size_t O_R0   = ((O_ECLS + 540800 + 255)/256)*256;   // 6,474,240
  constexpr size_t R0_SZ  = 44302336;   // HB -> (HX | HS)
  constexpr size_t O_R1   = O_R0 + R0_SZ;   // C1OUTc -> OBUF -> GIX(spans R2) -> Y1,YB
  constexpr size_t R1_SZ  = 44302336;
  constexpr size_t O_R2   = O_R1 + R1_SZ;   // C2OUTc -> QKVC -> GIX tail -> FCOUT
  constexpr size_t R2_SZ  = 33226752;
  constexpr size_t ARENA_END = O_R2 + R2_SZ;   // 128,305,664 B (~122.4 MiB)
  if (ws_size < ARENA_END) return;   // diagnostic: clean absmax fail (1.46875) = ws too small
  const size_t O_HB    = O_R0;
  const size_t O_HX    = O_R0;                 // 22,151,168 exchange layout
  const size_t O_HS    = O_R0 + 22151168;      // 22,151,168 (t,b)-row-major
  const size_t O_C1OUT = O_R1;                 // 34.6 MB chunk
  const size_t O_OBUF  = O_R1;                 // 44.3 MB; in-place DELTA1; then F1/DELTA2
  const size_t O_GIX   = O_R1;                 // 66.45 MB bf16, spans R1+R2
  const size_t O_Y1    = O_R1;                 // 22.2 MB bf16 (GIX dead post-GRU)
  const size_t O_YB    = O_R1 + 22151168;
  const size_t O_C2OUT = O_R2;                 // 24.9 MB chunk
  const size_t O_QKVC  = O_R2;                 // 33.2 MB chunk
  const size_t O_FCOUT = O_R2;                 // 5.5 MB f32 (after GIX dead)

  zero_kernel<<<1, 64, 0, stream>>>((unsigned*)(ws + O_BAR), 64);

  // weight conversion / reorder
  f2b_kernel<<<(3*768*256)/256, 256, 0, stream>>>(qkv_w, (u16*)(ws+O_QKVW), 3*768*256);
  f2b_kernel<<<(3*256*256)/256, 256, 0, stream>>>(out_w, (u16*)(ws+O_OUTW), 3*256*256);
  f2b_kernel<<<(3*256*256)/256, 256, 0, stream>>>(ff1_w, (u16*)(ws+O_FF1W), 3*256*256);
  f2b_kernel<<<(3*256*256)/256, 256, 0, stream>>>(ff2_w, (u16*)(ws+O_FF2W), 3*256*256);
  f2b_kernel<<<(1536*256)/256, 256, 0, stream>>>(g_wih, (u16*)(ws+O_WIHW), 1536*256);
  f2b_kernel<<<(512*512)/256, 256, 0, stream>>>(fc1_w, (u16*)(ws+O_FC1W), 512*512);
  reorder_pf_kernel<<<(256*1152)/256, 256, 0, stream>>>(pf_w, (u16*)(ws+O_PFW));
  reorder_w2_kernel<<<(128*576)/256, 256, 0, stream>>>(c2_w, (u16*)(ws+O_W2K));
  fc2pad_kernel<<<(64*512)/256, 256, 0, stream>>>(fc2_w, fc2_b, (u16*)(ws+O_FC2W), (float*)(ws+O_FC2B));
  w1t_kernel<<<(32*9*64)/256, 256, 0, stream>>>(c1_w, (float*)(ws+O_W1T));
  term2_kernel<<<169*25, 64, 0, stream>>>(c1_w, c1_b, (float*)(ws+O_T2));
  s2_kernel<<<1, 128, 0, stream>>>(bn2_g, (float*)(ws+O_S2));

  // token pieces
  mv_kernel<<<128, 256, 0, stream>>>(map_vec, mv_w, mv_b, (float*)(ws+O_MV));
  pos_kernel<<<169, 256, 0, stream>>>(row_e, col_e, pos_w, pos_b, (float*)(ws+O_POS));
  ecls_kernel<<<(21632*25+255)/256, 256, 0, stream>>>(tm, (u8*)(ws+O_ECLS));
  token_kernel<<<21632, 256, 0, stream>>>(tm, te, (const float*)(ws+O_MV), (const float*)(ws+O_POS),
      (u16*)(ws+O_HB));

  // conv pipeline, 2 chunks of 64 batches (10816 patches each)
  for (int cc = 0; cc < 2; cc++){
    const int nbase = cc*10816;
    conv1_kernel<<<338, 256, 0, stream>>>((const u8*)(ws+O_ECLS), (const float*)(ws+O_W1T),
        (const float*)(ws+O_T2), bn1_g, bn1_b, (u16*)(ws+O_C1OUT), nbase);
    gemm_conv2<<<dim3(2,1521), 256, 0, stream>>>((const u16*)(ws+O_C1OUT), (const u16*)(ws+O_W2K),
        c2_b, (const float*)(ws+O_S2), bn2_b, (u16*)(ws+O_C2OUT));
    gemm_bt<4><<<dim3(1,169), 256, 0, stream>>>((const u16*)(ws+O_C2OUT), 1152, (const u16*)(ws+O_PFW),
        pf_b, nullptr, nullptr, nullptr, (u16*)(ws+O_HB) + (size_t)nbase*1024 + 768, 1024, 256, 1152, 0, 0);
  }

  // transformer layers
  for (int l=0; l<3; l++){
    for (int cc = 0; cc < 4; cc++){          // 21632 token-rows (5408 seqs) per chunk
      gemm_bt<4><<<dim3(3,338), 256, 0, stream>>>((const u16*)(ws+O_HB) + (size_t)cc*21632*256, 256,
          (const u16*)(ws+O_QKVW) + (size_t)l*768*256, qkv_b + l*768, nullptr, nullptr,
          nullptr, (u16*)(ws+O_QKVC), 768, 768, 256, 0, 0);
      attn_kernel<<<1352, 256, 0, stream>>>((const u16*)(ws+O_QKVC),
          (u16*)(ws+O_OBUF) + (size_t)cc*5408*4*256);
    }
    gemm_bt<4><<<dim3(1,1352), 256, 0, stream>>>((const u16*)(ws+O_OBUF), 256,
        (const u16*)(ws+O_OUTW) + (size_t)l*256*256, out_b + l*256, nullptr, nullptr,
        nullptr, (u16*)(ws+O_OBUF), 256, 256, 256, 0, 0);      // in-place -> DELTA1
    ln_kernel<4><<<21632, 256, 0, stream>>>((const u16*)(ws+O_OBUF), (const u16*)(ws+O_HB),
        ln1_g + l*256, ln1_b + l*256, (u16*)(ws+O_HB), 0);
    gemm_bt<4><<<dim3(1,1352), 256, 0, stream>>>((const u16*)(ws+O_HB), 256,
        (const u16*)(ws+O_FF1W) + (size_t)l*256*256, ff1_b + l*256, nullptr, nullptr,
        nullptr, (u16*)(ws+O_OBUF), 256, 256, 256, 1, 0);      // F1
    gemm_bt<4><<<dim3(1,1352), 256, 0, stream>>>((const u16*)(ws+O_OBUF), 256,
        (const u16*)(ws+O_FF2W) + (size_t)l*256*256, ff2_b + l*256, nullptr, nullptr,
        nullptr, (u16*)(ws+O_OBUF), 256, 256, 256, 0, 0);      // in-place -> DELTA2
    ln_kernel<4><<<21632, 256, 0, stream>>>((const u16*)(ws+O_OBUF), (const u16*)(ws+O_HB),
        ln2_g + l*256, ln2_b + l*256, (u16*)(ws+O_HB), 0);
  }

  // GRU input projection -> swizzled giX[t][c][gate][b][16] (omode=1)
  gemm_bt<4><<<dim3(6,338), 256, 0, stream>>>((const u16*)(ws+O_HB), 1024, (const u16*)(ws+O_WIHW),
      g_bih, nullptr, nullptr, nullptr, (u16*)(ws+O_GIX), 1536, 1536, 256, 0, 1);
  gru_kernel<<<32, 256, 0, stream>>>((const u16*)(ws+O_GIX), g_whh, g_bhh,
      (u16*)(ws+O_HX), (unsigned*)(ws+O_BAR));
  unswz_kernel<<<(169*128*512)/256, 256, 0, stream>>>((const u16*)(ws+O_HX), (u16*)(ws+O_HS));

  // head (rows ordered m = t*128+b)
  gemm_bt<4><<<dim3(2,338), 256, 0, stream>>>((const u16*)(ws+O_HS), 512, (const u16*)(ws+O_FC1W),
      fc1_b, nullptr, nullptr, nullptr, (u16*)(ws+O_Y1), 512, 512, 512, 0, 0);
  ln_kernel<8><<<5408, 256, 0, stream>>>((const u16*)(ws+O_Y1), nullptr, fln_g, fln_b,
      (u16*)(ws+O_YB), 1);
  gemm_bt<1><<<dim3(1,338), 256, 0, stream>>>((const u16*)(ws+O_YB), 512, (const u16*)(ws+O_FC2W),
      (const float*)(ws+O_FC2B), nullptr, nullptr, (float*)(ws+O_FCOUT), nullptr, 64, 64, 512, 0, 0);
  outtr_kernel<<<(128*32*169+255)/256, 256, 0, stream>>>((const float*)(ws+O_FCOUT), (float*)d_out);
}

// Round 9
// 2921.311 us; speedup vs baseline: 1.8598x; 1.1628x over previous
//
#include <hip/hip_runtime.h>
#include <hip/hip_bf16.h>

typedef unsigned short u16;
typedef unsigned char u8;
typedef unsigned int u32;
typedef __attribute__((ext_vector_type(8))) short bf16x8;
typedef __attribute__((ext_vector_type(4))) float f32x4;
typedef __attribute__((ext_vector_type(4))) unsigned int u32x4;

__device__ __forceinline__ float us2f(u16 u){ return __uint_as_float(((unsigned)u)<<16); }
__device__ __forceinline__ u16 f2us(float f){
  __hip_bfloat16 h = __float2bfloat16(f);
  union { __hip_bfloat16 b; u16 s; } cv; cv.b = h; return cv.s;
}
__device__ __forceinline__ float gelu_f(float v){ return 0.5f*v*(1.f+erff(v*0.70710678118654752f)); }
__device__ __forceinline__ float sigm_f(float v){ return 1.f/(1.f+expf(-v)); }

#define BNSC 0.9999950000374997f  /* 1/sqrt(1+1e-5) */

// ---------------------------------------------------------------- fused prep
struct PrepArgs {
  const float *qkv_w, *out_w, *ff1_w, *ff2_w, *g_wih, *fc1_w, *pf_w, *c2_w, *fc2_w, *fc2_b;
  const float *c1_w, *c1_b, *bn2_g;
  const float *map_vec, *mv_w, *mv_b, *row_e, *col_e, *pos_w, *pos_b;
  const int *tm;
  u16 *qkvw_d, *outw_d, *ff1w_d, *ff2w_d, *wihw_d, *fc1w_d, *pfw_d, *w2k_d, *fc2w_d;
  float *fc2b_d, *w1t_d, *t2_d, *s2_d, *mv_d, *pos_d;
  u8 *ecls_d;
  unsigned *bar;
};
// segments (blocks of 256 threads)
#define SB_QKV 2304
#define SB_O   768
#define SB_WIH 1536
#define SB_FC1 1024
#define SB_PF  1152
#define SB_W2  288
#define SB_FC2 128
#define SB_W1T 72
#define SB_T2  1057
#define SB_MV  128
#define SB_POS 169
#define SB_EC  2113
#define PREP_GRID (1+SB_QKV+3*SB_O+SB_WIH+SB_FC1+SB_PF+SB_W2+SB_FC2+SB_W1T+SB_T2+SB_MV+SB_POS+SB_EC)

__global__ __launch_bounds__(256) void prep_kernel(PrepArgs a){
  int bb = blockIdx.x; const int tid = threadIdx.x;
  if (bb < 1){
    if (tid < 64)  a.bar[tid] = 0u;
    if (tid < 128) a.s2_d[tid] = a.bn2_g[tid]*BNSC;
    return;
  } bb -= 1;
  if (bb < SB_QKV){ int i = bb*256+tid; a.qkvw_d[i] = f2us(a.qkv_w[i]); return; } bb -= SB_QKV;
  if (bb < SB_O){ int i = bb*256+tid; a.outw_d[i] = f2us(a.out_w[i]); return; } bb -= SB_O;
  if (bb < SB_O){ int i = bb*256+tid; a.ff1w_d[i] = f2us(a.ff1_w[i]); return; } bb -= SB_O;
  if (bb < SB_O){ int i = bb*256+tid; a.ff2w_d[i] = f2us(a.ff2_w[i]); return; } bb -= SB_O;
  if (bb < SB_WIH){ int i = bb*256+tid; a.wihw_d[i] = f2us(a.g_wih[i]); return; } bb -= SB_WIH;
  if (bb < SB_FC1){ int i = bb*256+tid; a.fc1w_d[i] = f2us(a.fc1_w[i]); return; } bb -= SB_FC1;
  if (bb < SB_PF){                      // patch_fc_w k=c*9+pos -> k'=pos*128+c
    int i = bb*256+tid;
    int o = i/1152, kp = i%1152, pos = kp>>7, c = kp&127;
    a.pfw_d[i] = f2us(a.pf_w[o*1152 + c*9 + pos]); return;
  } bb -= SB_PF;
  if (bb < SB_W2){                      // c2_w -> [o][tap*64+ic]
    int i = bb*256+tid;
    int o = i/576, k = i%576, tap = k>>6, ic = k&63, ty = tap/3, tx = tap%3;
    a.w2k_d[i] = f2us(a.c2_w[((o*64 + ic)*3 + ty)*3 + tx]); return;
  } bb -= SB_W2;
  if (bb < SB_FC2){                     // fc2 pad to 64 rows
    int i = bb*256+tid;
    int o = i>>9, k = i&511;
    a.fc2w_d[i] = (o<32) ? f2us(a.fc2_w[o*512+k]) : (u16)0;
    if (i < 64) a.fc2b_d[i] = (i<32) ? a.fc2_b[i] : 0.f;
    return;
  } bb -= SB_FC2;
  if (bb < SB_W1T){                     // W1T[e][tap][o] = c1_w[o][e][tap]
    int i = bb*256+tid;
    int c = i/576, r = i%576, tap = r>>6, o = r&63;
    a.w1t_d[i] = a.c1_w[(o*33 + c)*9 + tap]; return;
  } bb -= SB_W1T;
  if (bb < SB_T2){                      // term2
    int i = bb*256+tid; if (i >= 169*25*64) return;
    int blk = i/64, o = i%64;
    int p = blk/25, op = blk%25, oy = op/5, ox = op%5;
    int yp = p/13, xp = p%13;
    float acc = a.c1_b[o];
    for (int dy=0; dy<3; dy++) for (int dx=0; dx<3; dx++){
      int Y = oy+dy-1, X = ox+dx-1;
      if (Y<0||Y>4||X<0||X>4) continue;
      int rr = yp + Y - 4, cc = xp + X - 2;
      bool m = (rr>=0) && (cc>=0) && (cc<13) && !(Y==4 && X>=2);
      if (m) acc += a.c1_w[(o*33 + 32)*9 + dy*3 + dx];
    }
    a.t2_d[((long)p*25 + op)*64 + o] = acc; return;
  } bb -= SB_T2;
  if (bb < SB_MV){                      // mv = map_vec @ mv_w.T + mv_b
    int i = bb*256+tid;
    int bi = i>>8, o = i&255;
    float acc = a.mv_b[o];
    for (int k=0;k<32;k++) acc += a.map_vec[bi*32+k]*a.mv_w[o*32+k];
    a.mv_d[i] = acc; return;
  } bb -= SB_MV;
  if (bb < SB_POS){                     // pos
    int i = bb*256+tid;
    int p = i>>8, o = i&255;
    int y = p/13, x = p%13;
    const float* wr = a.pos_w + o*512;
    float acc = a.pos_b[o];
    for (int k=0;k<256;k++) acc += a.row_e[y*256+k]*wr[k];
    for (int k=0;k<256;k++) acc += a.col_e[x*256+k]*wr[256+k];
    a.pos_d[i] = acc; return;
  } bb -= SB_POS;
  {                                     // ecls
    int id = bb*256+tid; if (id >= 21632*25) return;
    int n = id/25, q = id%25, Y = q/5, X = q%5;
    int b = n/169, p = n%169, yp = p/13, xp = p%13;
    int rr = yp + X - 4, cc = xp + Y - 2;
    int val = 0;
    if (rr>=0 && cc>=0 && cc<13 && !(X==4 && Y>=2)) val = a.tm[b*169 + rr*13 + cc];
    a.ecls_d[id] = (u8)val;
  }
}

// conv1 gather + BN + gelu -> c1out[local n][25][64] bf16; patches [nbase, nbase+10816)
__global__ __launch_bounds__(256) void conv1_kernel(
    const u8* __restrict__ ec, const float* __restrict__ w1t, const float* __restrict__ t2,
    const float* __restrict__ bn1g, const float* __restrict__ bn1b, u16* __restrict__ c1out,
    int nbase){
  __shared__ __align__(16) u16 w1s[32*9*64];
  __shared__ u8 ecs[32*25];
  const int tid = threadIdx.x, nl0 = blockIdx.x*32;
  for (int i=tid; i<32*9*64; i+=256) w1s[i] = f2us(w1t[i]);
  for (int i=tid; i<32*25;   i+=256) ecs[i] = ec[((long)nbase + nl0)*25 + i];
  __syncthreads();
  const int grp = tid>>6, o = tid&63;
  const float s1 = bn1g[o]*BNSC, t1 = bn1b[o];
  for (int it = grp; it < 800; it += 4){
    const int nl = it/25, op = it%25, oy = op/5, ox = op%5;
    const int n = nbase + nl0 + nl, p = n%169;
    float acc = t2[((long)p*25 + op)*64 + o];
    #pragma unroll
    for (int dy=0; dy<3; dy++)
      #pragma unroll
      for (int dx=0; dx<3; dx++){
        int Y = oy+dy-1, X = ox+dx-1;
        if (Y>=0 && Y<5 && X>=0 && X<5){
          int e = ecs[nl*25 + Y*5 + X];
          acc += us2f(w1s[(e*9 + dy*3+dx)*64 + o]);
        }
      }
    c1out[((long)(nl0+nl)*25 + op)*64 + o] = f2us(gelu_f(acc*s1 + t1));
  }
}

// ----------------------------------------------- generic bf16 GEMM C = A@W^T
// OM 0: row-major out (in-place safe when grid.x==1)
// OM 1: giX scatter [t][cblk][gate][b][16], m=b*169+t
// OM 2: LN epilogue (requires grid.x==1, N==64*NT): outB = LN(acc+bias+lbase)*lg+lb
// OM 3: head scatter: m=t*128+bb, n<32 -> outF[(bb*32+n)*169+t]
template<int NT, int OM>
__global__ __launch_bounds__(256) void gemm_bt(
    const u16* A, long lda, const u16* __restrict__ W,
    const float* __restrict__ bias,
    float* outF, u16* outB, long ldc, int N, int K, int act,
    const u16* __restrict__ lbase, const float* __restrict__ lg, const float* __restrict__ lb){
  __shared__ __align__(16) u16 As[64][72];
  __shared__ __align__(16) u16 Ws[NT][64][72];
  const int tid = threadIdx.x, wv = tid>>6, lane = tid&63;
  const int quad = lane>>4, l16 = lane&15;
  const int bm = blockIdx.y, bn = blockIdx.x;
  f32x4 acc[NT*4];
  #pragma unroll
  for (int i=0;i<NT*4;i++) acc[i] = (f32x4){0.f,0.f,0.f,0.f};
  const int sm = tid>>2, sk = (tid&3)<<4;
  const long arow = (long)(bm*64 + sm)*lda;
  for (int kb = 0; kb < K; kb += 64){
    int4 a0 = *(const int4*)(A + arow + kb + sk);
    int4 a1 = *(const int4*)(A + arow + kb + sk + 8);
    *(int4*)&As[sm][sk]   = a0;  *(int4*)&As[sm][sk+8] = a1;
    #pragma unroll
    for (int wt=0; wt<NT; wt++){
      const long wrow = (long)(bn*(64*NT) + wt*64 + sm)*K;
      int4 w0 = *(const int4*)(W + wrow + kb + sk);
      int4 w1 = *(const int4*)(W + wrow + kb + sk + 8);
      *(int4*)&Ws[wt][sm][sk]   = w0;  *(int4*)&Ws[wt][sm][sk+8] = w1;
    }
    __syncthreads();
    #pragma unroll
    for (int ks = 0; ks < 64; ks += 32){
      bf16x8 af = *(const bf16x8*)(&As[wv*16 + l16][ks + quad*8]);
      #pragma unroll
      for (int wt=0; wt<NT; wt++)
        #pragma unroll
        for (int s=0; s<4; s++){
          bf16x8 bfv = *(const bf16x8*)(&Ws[wt][s*16 + l16][ks + quad*8]);
          acc[wt*4+s] = __builtin_amdgcn_mfma_f32_16x16x32_bf16(af, bfv, acc[wt*4+s], 0, 0, 0);
        }
    }
    __syncthreads();
  }
  const int mb = bm*64 + wv*16 + quad*4;
  if (OM == 2){
    // x = acc + bias + base, in place
    #pragma unroll
    for (int wt=0; wt<NT; wt++)
      #pragma unroll
      for (int s=0; s<4; s++){
        const int n = wt*64 + s*16 + l16;
        const float bv = bias[n];
        #pragma unroll
        for (int r=0;r<4;r++)
          acc[wt*4+s][r] = acc[wt*4+s][r] + bv + us2f(lbase[(long)(mb+r)*N + n]);
      }
    float mean[4], rstd[4];
    #pragma unroll
    for (int r=0;r<4;r++){
      float s = 0.f;
      #pragma unroll
      for (int i=0;i<NT*4;i++) s += acc[i][r];
      s += __shfl_xor(s,1); s += __shfl_xor(s,2); s += __shfl_xor(s,4); s += __shfl_xor(s,8);
      mean[r] = s / N;
      float v = 0.f;
      #pragma unroll
      for (int i=0;i<NT*4;i++){ float d = acc[i][r]-mean[r]; v += d*d; }
      v += __shfl_xor(v,1); v += __shfl_xor(v,2); v += __shfl_xor(v,4); v += __shfl_xor(v,8);
      rstd[r] = rsqrtf(v/N + 1e-5f);
    }
    #pragma unroll
    for (int wt=0; wt<NT; wt++)
      #pragma unroll
      for (int s=0; s<4; s++){
        const int n = wt*64 + s*16 + l16;
        const float gv = lg[n], bvv = lb[n];
        #pragma unroll
        for (int r=0;r<4;r++)
          outB[(long)(mb+r)*ldc + n] = f2us((acc[wt*4+s][r]-mean[r])*rstd[r]*gv + bvv);
      }
    return;
  }
  #pragma unroll
  for (int wt=0; wt<NT; wt++)
    #pragma unroll
    for (int s=0; s<4; s++){
      const int n = bn*(64*NT) + wt*64 + s*16 + l16;
      const float bv = bias ? bias[n] : 0.f;
      #pragma unroll
      for (int r=0;r<4;r++){
        float v = acc[wt*4+s][r] + bv;
        if (act==1) v = fmaxf(v, 0.f);
        else if (act==2) v = gelu_f(v);
        if (OM == 1){
          const int m = mb + r, b = m/169, tt = m%169;
          const int gate = n>>9, cblk = (n>>4)&31, jl = n&15;
          outB[(((long)tt*32 + cblk)*3 + gate)*2048 + b*16 + jl] = f2us(v);
        } else if (OM == 3){
          if (n < 32){
            const int m = mb + r, t = m/128, b2 = m%128;
            outF[((long)b2*32 + n)*169 + t] = v;
          }
        } else {
          const long oo = (long)(mb + r)*ldc + n;
          if (outF) outF[oo] = v;
          if (outB) outB[oo] = f2us(v);
        }
      }
    }
}

// conv2 implicit-im2col GEMM
__global__ __launch_bounds__(256) void gemm_conv2(
    const u16* __restrict__ C1, const u16* __restrict__ W,
    const float* __restrict__ bias, const float* __restrict__ scale, const float* __restrict__ shift,
    u16* __restrict__ outB){
  __shared__ __align__(16) u16 As[64][72];
  __shared__ __align__(16) u16 Ws[64][72];
  const int tid = threadIdx.x, wv = tid>>6, lane = tid&63;
  const int quad = lane>>4, l16 = lane&15;
  const int bm = blockIdx.y, bn = blockIdx.x;
  f32x4 acc[4];
  #pragma unroll
  for (int i=0;i<4;i++) acc[i] = (f32x4){0.f,0.f,0.f,0.f};
  const int sm = tid>>2, sk = (tid&3)<<4;
  const int g = bm*64 + sm, n_ = g/9, pos = g%9, py = pos/3, px = pos%3;
  const long wrow = (long)(bn*64 + sm)*576;
  for (int tap = 0; tap < 9; tap++){
    const int kb = tap*64;
    const long aoff = ((long)n_*25 + (py + tap/3)*5 + (px + tap%3))*64 + sk;
    int4 a0 = *(const int4*)(C1 + aoff);
    int4 a1 = *(const int4*)(C1 + aoff + 8);
    int4 w0 = *(const int4*)(W + wrow + kb + sk);
    int4 w1 = *(const int4*)(W + wrow + kb + sk + 8);
    *(int4*)&As[sm][sk]   = a0;  *(int4*)&As[sm][sk+8] = a1;
    *(int4*)&Ws[sm][sk]   = w0;  *(int4*)&Ws[sm][sk+8] = w1;
    __syncthreads();
    #pragma unroll
    for (int ks = 0; ks < 64; ks += 32){
      bf16x8 af = *(const bf16x8*)(&As[wv*16 + l16][ks + quad*8]);
      #pragma unroll
      for (int nt=0; nt<4; nt++){
        bf16x8 bfv = *(const bf16x8*)(&Ws[nt*16 + l16][ks + quad*8]);
        acc[nt] = __builtin_amdgcn_mfma_f32_16x16x32_bf16(af, bfv, acc[nt], 0, 0, 0);
      }
    }
    __syncthreads();
  }
  const int mb = bm*64 + wv*16 + quad*4;
  #pragma unroll
  for (int nt=0; nt<4; nt++){
    const int n = bn*64 + nt*16 + l16;
    const float bv = bias[n], sc = scale[n], sh = shift[n];
    #pragma unroll
    for (int r=0;r<4;r++){
      float v = (acc[nt][r] + bv)*sc + sh;
      outB[(long)(mb + r)*128 + n] = f2us(gelu_f(v));
    }
  }
}

// tokens -> h bf16 [86528][256]; fills slots 0..2
__global__ void token_kernel(const int* __restrict__ tm, const float* __restrict__ te,
                             const float* __restrict__ mv, const float* __restrict__ pos,
                             u16* __restrict__ hB){
  const int n = blockIdx.x, k = threadIdx.x;
  const int b = n/169, p = n%169;
  const int prev = (p==0) ? 31 : tm[b*169 + p - 1];
  const long r0 = (long)n*1024;
  hB[r0 + k]        = f2us(te[prev*256 + k]);
  hB[r0 + 256 + k]  = f2us(mv[b*256 + k]);
  hB[r0 + 512 + k]  = f2us(pos[p*256 + k]);
}

// attention: seq of 4 tokens, 2 heads x 128; one wave per sequence
__global__ __launch_bounds__(256) void attn_kernel(const u16* __restrict__ qkv, u16* o){
  const int n = blockIdx.x*4 + (threadIdx.x>>6);
  const int lane = threadIdx.x & 63;
  float qv[4][2][2], kv[4][2][2], vv[4][2][2];
  #pragma unroll
  for (int tok=0; tok<4; tok++){
    const long rb = (long)(n*4+tok)*768;
    #pragma unroll
    for (int h=0; h<2; h++){
      unsigned u;
      u = *(const unsigned*)(qkv + rb +        h*128 + 2*lane); qv[tok][h][0]=us2f(u&0xffff); qv[tok][h][1]=us2f(u>>16);
      u = *(const unsigned*)(qkv + rb + 256 +  h*128 + 2*lane); kv[tok][h][0]=us2f(u&0xffff); kv[tok][h][1]=us2f(u>>16);
      u = *(const unsigned*)(qkv + rb + 512 +  h*128 + 2*lane); vv[tok][h][0]=us2f(u&0xffff); vv[tok][h][1]=us2f(u>>16);
    }
  }
  float sc[2][4][4];
  #pragma unroll
  for (int h=0; h<2; h++)
    #pragma unroll
    for (int qt=0; qt<4; qt++)
      #pragma unroll
      for (int kt=0; kt<4; kt++){
        float p_ = qv[qt][h][0]*kv[kt][h][0] + qv[qt][h][1]*kv[kt][h][1];
        for (int off=32; off; off>>=1) p_ += __shfl_xor(p_, off);
        sc[h][qt][kt] = p_ * 0.08838834764831845f;
      }
  #pragma unroll
  for (int h=0; h<2; h++)
    #pragma unroll
    for (int qt=0; qt<4; qt++){
      float m = fmaxf(fmaxf(sc[h][qt][0],sc[h][qt][1]),fmaxf(sc[h][qt][2],sc[h][qt][3]));
      float s = 0.f;
      #pragma unroll
      for (int kt=0; kt<4; kt++){ sc[h][qt][kt] = expf(sc[h][qt][kt]-m); s += sc[h][qt][kt]; }
      float inv = 1.f/s;
      #pragma unroll
      for (int kt=0; kt<4; kt++) sc[h][qt][kt] *= inv;
    }
  #pragma unroll
  for (int qt=0; qt<4; qt++)
    #pragma unroll
    for (int h=0; h<2; h++){
      float o0=0.f, o1=0.f;
      #pragma unroll
      for (int kt=0; kt<4; kt++){ o0 += sc[h][qt][kt]*vv[kt][h][0]; o1 += sc[h][qt][kt]*vv[kt][h][1]; }
      unsigned u = (unsigned)f2us(o0) | ((unsigned)f2us(o1)<<16);
      *(unsigned*)(o + (long)(n*4+qt)*256 + h*128 + 2*lane) = u;
    }
}

// LayerNorm (wave per row) — used only for the head fcln(+gelu)
template<int NPL>
__global__ __launch_bounds__(256) void ln_kernel(
    const u16* __restrict__ delta, const u16* __restrict__ base,
    const float* __restrict__ g, const float* __restrict__ b,
    u16* __restrict__ out, int do_gelu){
  const int D = NPL*64;
  const int row = blockIdx.x*4 + (threadIdx.x>>6);
  const int lane = threadIdx.x & 63;
  const long ro = (long)row*D;
  float x[NPL];
  float s = 0.f;
  #pragma unroll
  for (int i=0;i<NPL;i++){
    float v = us2f(delta[ro + i*64 + lane]);
    if (base) v += us2f(base[ro + i*64 + lane]);
    x[i] = v; s += v;
  }
  for (int off=32; off; off>>=1) s += __shfl_xor(s, off);
  const float mean = s / D;
  float var = 0.f;
  #pragma unroll
  for (int i=0;i<NPL;i++){ float dd = x[i]-mean; var += dd*dd; }
  for (int off=32; off; off>>=1) var += __shfl_xor(var, off);
  const float rs = rsqrtf(var/D + 1e-5f);
  #pragma unroll
  for (int i=0;i<NPL;i++){
    float y = (x[i]-mean)*rs*g[i*64+lane] + b[i*64+lane];
    if (do_gelu) y = gelu_f(y);
    out[ro + i*64 + lane] = f2us(y);
  }
}

// GRU v6: as R8 (validated 940us) + direct row-major hs stores after barrier release.
__global__ __launch_bounds__(256) void gru_kernel(
    const u16* __restrict__ gix, const float* __restrict__ whh,
    const float* __restrict__ bhh, u16* __restrict__ hx, u16* __restrict__ hs,
    unsigned* __restrict__ bar){
  __shared__ __align__(16) u16 Wl[48][520];
  __shared__ __align__(16) u16 hbuf[2048];
  const int c = blockIdx.x, tid = threadIdx.x;
  const int wv = tid>>6, lane = tid&63, quad = lane>>4, l16 = lane&15;
  for (int idx = tid; idx < 48*512; idx += 256){
    int g = idx >> 9, k = idx & 511;
    int gate = g >> 4, jl = g & 15;
    Wl[g][k] = f2us(whh[((gate<<9) + (c<<4) + jl)*512 + k]);
  }
  const int j = (c<<4) + l16;
  const float bh_r = bhh[j], bh_z = bhh[512+j], bh_n = bhh[1024+j];
  __syncthreads();
  float hold[2][4] = {{0.f,0.f,0.f,0.f},{0.f,0.f,0.f,0.f}};
  const int jlo = (quad&1)*8, jhiadd = quad>>1;
  for (int t=0; t<169; t++){
    const u16* gbase = gix + ((long)t*32 + c)*3*2048;
    float gr_[2][4], gz_[2][4], gn_[2][4];
    #pragma unroll
    for (int mt=0; mt<2; mt++)
      #pragma unroll
      for (int r=0; r<4; r++){
        const int b = (2*wv+mt)*16 + quad*4 + r;
        gr_[mt][r] = us2f(gbase[       b*16 + l16]);
        gz_[mt][r] = us2f(gbase[2048 + b*16 + l16]);
        gn_[mt][r] = us2f(gbase[4096 + b*16 + l16]);
      }
    if (t>0){
      if (tid==0){
        while (__hip_atomic_load(bar, __ATOMIC_RELAXED, __HIP_MEMORY_SCOPE_AGENT) < (unsigned)(32*t))
          __builtin_amdgcn_s_sleep(1);
      }
      __syncthreads();
    }
    f32x4 acc[2][3];
    #pragma unroll
    for (int mt=0; mt<2; mt++)
      #pragma unroll
      for (int g3=0; g3<3; g3++) acc[mt][g3] = (f32x4){0.f,0.f,0.f,0.f};
    if (t>0){
      const long tb = (long)(t-1)*65536;
      const int b0 = (2*wv+0)*16 + l16, b1 = (2*wv+1)*16 + l16;
      bf16x8 av0[16], av1[16];
      #pragma unroll
      for (int ii=0; ii<16; ii++){
        const long off = tb + (long)(ii*2 + jhiadd)*2048 + jlo;
        const u16* p0 = hx + off + b0*16;
        const u16* p1 = hx + off + b1*16;
        asm volatile("global_load_dwordx4 %0, %1, off sc0 sc1" : "=v"(av0[ii]) : "v"(p0));
        asm volatile("global_load_dwordx4 %0, %1, off sc0 sc1" : "=v"(av1[ii]) : "v"(p1));
      }
      asm volatile("s_waitcnt vmcnt(0)" ::: "memory");
      #pragma unroll
      for (int ii=0; ii<16; ii++){
        asm volatile("" : "+v"(av0[ii]));
        asm volatile("" : "+v"(av1[ii]));
      }
      #pragma unroll
      for (int ii=0; ii<16; ii++){
        const int ks = ii*32;
        #pragma unroll
        for (int g3=0; g3<3; g3++){
          bf16x8 bfv = *(const bf16x8*)(&Wl[g3*16 + l16][ks + quad*8]);
          acc[0][g3] = __builtin_amdgcn_mfma_f32_16x16x32_bf16(av0[ii], bfv, acc[0][g3], 0,0,0);
          acc[1][g3] = __builtin_amdgcn_mfma_f32_16x16x32_bf16(av1[ii], bfv, acc[1][g3], 0,0,0);
        }
      }
    }
    u16 hbv[2][4];
    #pragma unroll
    for (int mt=0; mt<2; mt++)
      #pragma unroll
      for (int r=0; r<4; r++){
        const int b = (2*wv+mt)*16 + quad*4 + r;
        float rr = sigm_f(gr_[mt][r] + acc[mt][0][r] + bh_r);
        float zz = sigm_f(gz_[mt][r] + acc[mt][1][r] + bh_z);
        float nn = tanhf (gn_[mt][r] + rr*(acc[mt][2][r] + bh_n));
        float h = (1.f-zz)*nn + zz*hold[mt][r];
        hold[mt][r] = h;
        hbv[mt][r] = f2us(h);
        hbuf[b*16 + l16] = hbv[mt][r];
      }
    __syncthreads();
    {
      u16* dst = hx + (long)t*65536 + c*2048 + tid*8;
      u32x4 val = *(const u32x4*)((const u32*)hbuf + tid*4);
      asm volatile("global_store_dwordx4 %0, %1, off sc0 sc1" :: "v"(dst), "v"(val) : "memory");
    }
    asm volatile("s_waitcnt vmcnt(0)" ::: "memory");
    __syncthreads();
    if (tid==0) __hip_atomic_fetch_add(bar, 1u, __ATOMIC_RELAXED, __HIP_MEMORY_SCOPE_AGENT);
    // off-critical-path row-major hs for the head GEMM (drains in background)
    #pragma unroll
    for (int mt=0; mt<2; mt++)
      #pragma unroll
      for (int r=0; r<4; r++){
        const int b = (2*wv+mt)*16 + quad*4 + r;
        hs[((long)(t*128 + b))*512 + j] = hbv[mt][r];
      }
  }
}

// ---------------------------------------------------------------- host
extern "C" void kernel_launch(void* const* d_in, const int* in_sizes, int n_in,
                              void* d_out, int out_size, void* d_ws, size_t ws_size,
                              hipStream_t stream){
  (void)in_sizes; (void)n_in; (void)out_size;
  const float* map_vec = (const float*)d_in[0];
  const int*   tm      = (const int*)  d_in[1];
  const float* mv_w  = (const float*)d_in[2];
  const float* mv_b  = (const float*)d_in[3];
  const float* te    = (const float*)d_in[4];
  const float* row_e = (const float*)d_in[5];
  const float* col_e = (const float*)d_in[6];
  const float* pos_w = (const float*)d_in[7];
  const float* pos_b = (const float*)d_in[8];
  const float* c1_w  = (const float*)d_in[9];
  const float* c1_b  = (const float*)d_in[10];
  const float* bn1_g = (const float*)d_in[11];
  const float* bn1_b = (const float*)d_in[12];
  const float* c2_w  = (const float*)d_in[13];
  const float* c2_b  = (const float*)d_in[14];
  const float* bn2_g = (const float*)d_in[15];
  const float* bn2_b = (const float*)d_in[16];
  const float* pf_w  = (const float*)d_in[17];
  const float* pf_b  = (const float*)d_in[18];
  const float* qkv_w = (const float*)d_in[19];
  const float* qkv_b = (const float*)d_in[20];
  const float* out_w = (const float*)d_in[21];
  const float* out_b = (const float*)d_in[22];
  const float* ln1_g = (const float*)d_in[23];
  const float* ln1_b = (const float*)d_in[24];
  const float* ff1_w = (const float*)d_in[25];
  const float* ff1_b = (const float*)d_in[26];
  const float* ff2_w = (const float*)d_in[27];
  const float* ff2_b = (const float*)d_in[28];
  const float* ln2_g = (const float*)d_in[29];
  const float* ln2_b = (const float*)d_in[30];
  const float* g_wih = (const float*)d_in[31];
  const float* g_whh = (const float*)d_in[32];
  const float* g_bih = (const float*)d_in[33];
  const float* g_bhh = (const float*)d_in[34];
  const float* fc1_w = (const float*)d_in[35];
  const float* fc1_b = (const float*)d_in[36];
  const float* fln_g = (const float*)d_in[37];
  const float* fln_b = (const float*)d_in[38];
  const float* fc2_w = (const float*)d_in[39];
  const float* fc2_b = (const float*)d_in[40];

  char* ws = (char*)d_ws;
  constexpr size_t O_BAR  = 0;
  constexpr size_t O_QKVW = 256;
  constexpr size_t O_OUTW = O_QKVW + 1179648;
  constexpr size_t O_FF1W = O_OUTW + 393216;
  constexpr size_t O_FF2W = O_FF1W + 393216;
  constexpr size_t O_WIHW = O_FF2W + 393216;
  constexpr size_t O_FC1W = O_WIHW + 786432;
  constexpr size_t O_PFW  = O_FC1W + 524288;
  constexpr size_t O_W2K  = O_PFW  + 589824;
  constexpr size_t O_FC2W = O_W2K  + 147456;
  constexpr size_t O_FC2B = O_FC2W + 65536;
  constexpr size_t O_W1T  = O_FC2B + 256;
  constexpr size_t O_T2   = O_W1T  + 73728;
  constexpr size_t O_S2   = O_T2   + 1081600;
  constexpr size_t O_MV   = O_S2   + 512;
  constexpr size_t O_POS  = O_MV   + 131072;
  constexpr size_t O_ECLS = O_POS  + 173056;
  constexpr size_t O_R0   = ((O_ECLS + 540800 + 255)/256)*256;
  constexpr size_t R0_SZ  = 44302336;   // HB -> (HX | HS)
  constexpr size_t O_R1   = O_R0 + R0_SZ;
  constexpr size_t R1_SZ  = 44302336;
  constexpr size_t O_R2   = O_R1 + R1_SZ;
  constexpr size_t R2_SZ  = 33226752;
  constexpr size_t ARENA_END = O_R2 + R2_SZ;   // ~122.4 MiB
  if (ws_size < ARENA_END) return;
  const size_t O_HB    = O_R0;
  const size_t O_HX    = O_R0;
  const size_t O_HS    = O_R0 + 22151168;
  const size_t O_C1OUT = O_R1;
  const size_t O_OBUF  = O_R1;
  const size_t O_GIX   = O_R1;
  const size_t O_Y1    = O_R1;
  const size_t O_YB    = O_R1 + 22151168;
  const size_t O_C2OUT = O_R2;
  const size_t O_QKVC  = O_R2;

  PrepArgs pa;
  pa.qkv_w=qkv_w; pa.out_w=out_w; pa.ff1_w=ff1_w; pa.ff2_w=ff2_w; pa.g_wih=g_wih;
  pa.fc1_w=fc1_w; pa.pf_w=pf_w; pa.c2_w=c2_w; pa.fc2_w=fc2_w; pa.fc2_b=fc2_b;
  pa.c1_w=c1_w; pa.c1_b=c1_b; pa.bn2_g=bn2_g;
  pa.map_vec=map_vec; pa.mv_w=mv_w; pa.mv_b=mv_b; pa.row_e=row_e; pa.col_e=col_e;
  pa.pos_w=pos_w; pa.pos_b=pos_b; pa.tm=tm;
  pa.qkvw_d=(u16*)(ws+O_QKVW); pa.outw_d=(u16*)(ws+O_OUTW); pa.ff1w_d=(u16*)(ws+O_FF1W);
  pa.ff2w_d=(u16*)(ws+O_FF2W); pa.wihw_d=(u16*)(ws+O_WIHW); pa.fc1w_d=(u16*)(ws+O_FC1W);
  pa.pfw_d=(u16*)(ws+O_PFW); pa.w2k_d=(u16*)(ws+O_W2K); pa.fc2w_d=(u16*)(ws+O_FC2W);
  pa.fc2b_d=(float*)(ws+O_FC2B); pa.w1t_d=(float*)(ws+O_W1T); pa.t2_d=(float*)(ws+O_T2);
  pa.s2_d=(float*)(ws+O_S2); pa.mv_d=(float*)(ws+O_MV); pa.pos_d=(float*)(ws+O_POS);
  pa.ecls_d=(u8*)(ws+O_ECLS); pa.bar=(unsigned*)(ws+O_BAR);
  prep_kernel<<<PREP_GRID, 256, 0, stream>>>(pa);

  token_kernel<<<21632, 256, 0, stream>>>(tm, te, (const float*)(ws+O_MV), (const float*)(ws+O_POS),
      (u16*)(ws+O_HB));

  for (int cc = 0; cc < 2; cc++){
    const int nbase = cc*10816;
    conv1_kernel<<<338, 256, 0, stream>>>((const u8*)(ws+O_ECLS), (const float*)(ws+O_W1T),
        (const float*)(ws+O_T2), bn1_g, bn1_b, (u16*)(ws+O_C1OUT), nbase);
    gemm_conv2<<<dim3(2,1521), 256, 0, stream>>>((const u16*)(ws+O_C1OUT), (const u16*)(ws+O_W2K),
        c2_b, (const float*)(ws+O_S2), bn2_b, (u16*)(ws+O_C2OUT));
    gemm_bt<4,0><<<dim3(1,169), 256, 0, stream>>>((const u16*)(ws+O_C2OUT), 1152, (const u16*)(ws+O_PFW),
        pf_b, nullptr, (u16*)(ws+O_HB) + (size_t)nbase*1024 + 768, 1024, 256, 1152, 0,
        nullptr, nullptr, nullptr);
  }

  for (int l=0; l<3; l++){
    for (int cc = 0; cc < 4; cc++){
      gemm_bt<4,0><<<dim3(3,338), 256, 0, stream>>>((const u16*)(ws+O_HB) + (size_t)cc*21632*256, 256,
          (const u16*)(ws+O_QKVW) + (size_t)l*768*256, qkv_b + l*768,
          nullptr, (u16*)(ws+O_QKVC), 768, 768, 256, 0, nullptr, nullptr, nullptr);
      attn_kernel<<<1352, 256, 0, stream>>>((const u16*)(ws+O_QKVC),
          (u16*)(ws+O_OBUF) + (size_t)cc*5408*4*256);
    }
    // out-proj + residual + LN1 fused -> HB
    gemm_bt<4,2><<<dim3(1,1352), 256, 0, stream>>>((const u16*)(ws+O_OBUF), 256,
        (const u16*)(ws+O_OUTW) + (size_t)l*256*256, out_b + l*256,
        nullptr, (u16*)(ws+O_HB), 256, 256, 256, 0,
        (const u16*)(ws+O_HB), ln1_g + l*256, ln1_b + l*256);
    // ff1 + relu -> OBUF
    gemm_bt<4,0><<<dim3(1,1352), 256, 0, stream>>>((const u16*)(ws+O_HB), 256,
        (const u16*)(ws+O_FF1W) + (size_t)l*256*256, ff1_b + l*256,
        nullptr, (u16*)(ws+O_OBUF), 256, 256, 256, 1, nullptr, nullptr, nullptr);
    // ff2 + residual + LN2 fused -> HB
    gemm_bt<4,2><<<dim3(1,1352), 256, 0, stream>>>((const u16*)(ws+O_OBUF), 256,
        (const u16*)(ws+O_FF2W) + (size_t)l*256*256, ff2_b + l*256,
        nullptr, (u16*)(ws+O_HB), 256, 256, 256, 0,
        (const u16*)(ws+O_HB), ln2_g + l*256, ln2_b + l*256);
  }

  // GRU input projection -> swizzled giX (OM=1)
  gemm_bt<4,1><<<dim3(6,338), 256, 0, stream>>>((const u16*)(ws+O_HB), 1024, (const u16*)(ws+O_WIHW),
      g_bih, nullptr, (u16*)(ws+O_GIX), 1536, 1536, 256, 0, nullptr, nullptr, nullptr);
  gru_kernel<<<32, 256, 0, stream>>>((const u16*)(ws+O_GIX), g_whh, g_bhh,
      (u16*)(ws+O_HX), (u16*)(ws+O_HS), (unsigned*)(ws+O_BAR));

  // head (rows m = t*128+b)
  gemm_bt<4,0><<<dim3(2,338), 256, 0, stream>>>((const u16*)(ws+O_HS), 512, (const u16*)(ws+O_FC1W),
      fc1_b, nullptr, (u16*)(ws+O_Y1), 512, 512, 512, 0, nullptr, nullptr, nullptr);
  ln_kernel<8><<<5408, 256, 0, stream>>>((const u16*)(ws+O_Y1), nullptr, fln_g, fln_b,
      (u16*)(ws+O_YB), 1);
  gemm_bt<1,3><<<dim3(1,338), 256, 0, stream>>>((const u16*)(ws+O_YB), 512, (const u16*)(ws+O_FC2W),
      (const float*)(ws+O_FC2B), (float*)d_out, nullptr, 64, 64, 512, 0, nullptr, nullptr, nullptr);
}